// Round 6
// baseline (5727.830 us; speedup 1.0000x reference)
//
#include <hip/hip_runtime.h>

#define N_NODES 100000
#define N_EDGES 1600000
#define DIM 128
#define NCLS 64
#define NG 128
#define BN_EPS 1e-5f

typedef __attribute__((ext_vector_type(8))) short s16x8;
typedef __attribute__((ext_vector_type(4))) float f32x4;
#define MFMA_BF16 __builtin_amdgcn_mfma_f32_16x16x32_bf16

// split 8 f32 into bf16 hi + bf16 lo (truncation; dropped lo*lo term ~2^-18 rel)
__device__ __forceinline__ void f2hl8(float4 v0, float4 v1, s16x8& h8, s16x8& l8) {
    float vv[8] = {v0.x, v0.y, v0.z, v0.w, v1.x, v1.y, v1.z, v1.w};
#pragma unroll
    for (int i = 0; i < 8; ++i) {
        unsigned u = __float_as_uint(vv[i]);
        short h = (short)(u >> 16);
        float r = vv[i] - __uint_as_float(u & 0xFFFF0000u);
        short l = (short)(__float_as_uint(r) >> 16);
        h8[i] = h;
        l8[i] = l;
    }
}

__device__ __forceinline__ float4 relu4(float4 v) {
    v.x = fmaxf(v.x, 0.f); v.y = fmaxf(v.y, 0.f);
    v.z = fmaxf(v.z, 0.f); v.w = fmaxf(v.w, 0.f);
    return v;
}

// ---------------- edge-order scatter aggregation ----------------
// One wave handles 2 edges (half-wave each, float4/lane over D=128).
// xe streamed sequentially; agg[dst] accumulated via f32 atomics (L2/LLC-resident).
__global__ __launch_bounds__(256) void k_scat(
        const float* __restrict__ F, const float* __restrict__ xe,
        const int* __restrict__ src, const int* __restrict__ dst,
        float* __restrict__ agg, int* __restrict__ cnt,
        const float* __restrict__ bnsc, int applyBN, int doCnt) {
    int wid = (blockIdx.x * 256 + threadIdx.x) >> 6;
    int lane = threadIdx.x & 63;
    int half = lane >> 5, l = lane & 31;
    long e = (long)wid * 2 + half;
    if (e >= N_EDGES) return;
    int s = src[e], d = dst[e];
    float4 a = *reinterpret_cast<const float4*>(&F[(size_t)s * DIM + l * 4]);
    float4 b = *reinterpret_cast<const float4*>(&xe[(size_t)e * DIM + l * 4]);
    if (applyBN) {
        float4 sc = *reinterpret_cast<const float4*>(&bnsc[l * 4]);
        float4 sh = *reinterpret_cast<const float4*>(&bnsc[DIM + l * 4]);
        a.x = fmaxf(a.x * sc.x + sh.x, 0.f);
        a.y = fmaxf(a.y * sc.y + sh.y, 0.f);
        a.z = fmaxf(a.z * sc.z + sh.z, 0.f);
        a.w = fmaxf(a.w * sc.w + sh.w, 0.f);
    }
    float4 m;
    m.x = fmaxf(a.x + b.x, 0.f);
    m.y = fmaxf(a.y + b.y, 0.f);
    m.z = fmaxf(a.z + b.z, 0.f);
    m.w = fmaxf(a.w + b.w, 0.f);
    float* ap = &agg[(size_t)d * DIM + l * 4];
    atomicAdd(ap + 0, m.x);
    atomicAdd(ap + 1, m.y);
    atomicAdd(ap + 2, m.z);
    atomicAdd(ap + 3, m.w);
    if (doCnt && l == 0) atomicAdd(&cnt[d], 1);
}

// ---------------- weight prep (ALL matrices in one launch) ----------------
// frag t = ct*256 + ks*64 + lane holds W[col=ct*16+(lane&15)][k=ks*32+(lane>>4)*8+e]
__global__ void k_wprep_all(const float* __restrict__ Wl0, const float* __restrict__ Wr0,
                            const float* __restrict__ Wl1, const float* __restrict__ Wr1,
                            const float* __restrict__ Wp,
                            short* __restrict__ fWl0h, short* __restrict__ fWl0l,
                            short* __restrict__ fWr0h, short* __restrict__ fWr0l,
                            short* __restrict__ fWl1h, short* __restrict__ fWl1l,
                            short* __restrict__ fWr1h, short* __restrict__ fWr1l,
                            short* __restrict__ fWph, short* __restrict__ fWpl) {
    int b = blockIdx.x;          // 0..35
    const float* W; short* hi; short* lo; int ct;
    if (b < 8)       { W = Wl0; hi = fWl0h; lo = fWl0l; ct = b; }
    else if (b < 16) { W = Wr0; hi = fWr0h; lo = fWr0l; ct = b - 8; }
    else if (b < 24) { W = Wl1; hi = fWl1h; lo = fWl1l; ct = b - 16; }
    else if (b < 32) { W = Wr1; hi = fWr1h; lo = fWr1l; ct = b - 24; }
    else             { W = Wp;  hi = fWph;  lo = fWpl;  ct = b - 32; }
    int tt = threadIdx.x;
    int lane = tt & 63, ks = (tt >> 6) & 3;
    int row = ct * 16 + (lane & 15);
    int k0 = ks * 32 + ((lane >> 4) << 3);
    float4 v0 = *reinterpret_cast<const float4*>(&W[(size_t)row * DIM + k0]);
    float4 v1 = *reinterpret_cast<const float4*>(&W[(size_t)row * DIM + k0 + 4]);
    s16x8 h8, l8;
    f2hl8(v0, v1, h8, l8);
    int t = ct * 256 + ks * 64 + lane;
    *reinterpret_cast<s16x8*>(&hi[(size_t)t * 8]) = h8;
    *reinterpret_cast<s16x8*>(&lo[(size_t)t * 8]) = l8;
}

// ---------------- MFMA dual GEMM (no LDS staging, 2 strips/wave) ------------
// OUT = (A/cnt)@W1^T + bn?(B)@W2^T + bias   (+ optional BN stats)
// block = 128 nodes, 4 waves; wave w: rows [n0+16w, +16) and [n0+64+16w, +16)
__global__ __launch_bounds__(256) void k_gemm2(
        const float* __restrict__ A, const float* __restrict__ B,
        const int* __restrict__ cntp,
        const short* __restrict__ fW1h, const short* __restrict__ fW1l,
        const short* __restrict__ fW2h, const short* __restrict__ fW2l,
        const float* __restrict__ bias, float* __restrict__ OUT,
        float* __restrict__ bnacc, const float* __restrict__ bnsc,
        int doBN, int bnB) {
    int t = threadIdx.x, w = t >> 6, l = t & 63;
    int n0 = blockIdx.x * 128;
    int r = l & 15, kh = l >> 4;
    int row0 = n0 + w * 16 + r;
    int row1 = row0 + 64;
    int n_0 = min(row0, N_NODES - 1);
    int n_1 = min(row1, N_NODES - 1);
    float invc0 = 1.f / (float)max(cntp[n_0], 1);
    float invc1 = 1.f / (float)max(cntp[n_1], 1);

    f32x4 acc0[8], acc1[8];
#pragma unroll
    for (int ct = 0; ct < 8; ++ct) {
        acc0[ct] = (f32x4){0.f, 0.f, 0.f, 0.f};
        acc1[ct] = (f32x4){0.f, 0.f, 0.f, 0.f};
    }
    const s16x8* w1h = (const s16x8*)fW1h;
    const s16x8* w1l = (const s16x8*)fW1l;
    const s16x8* w2h = (const s16x8*)fW2h;
    const s16x8* w2l = (const s16x8*)fW2l;

#pragma unroll
    for (int ks = 0; ks < 4; ++ks) {
        int kb = ks * 32 + kh * 8;
        float4 va0 = *reinterpret_cast<const float4*>(&A[(size_t)n_0 * DIM + kb]);
        float4 va1 = *reinterpret_cast<const float4*>(&A[(size_t)n_0 * DIM + kb + 4]);
        float4 vb0 = *reinterpret_cast<const float4*>(&B[(size_t)n_0 * DIM + kb]);
        float4 vb1 = *reinterpret_cast<const float4*>(&B[(size_t)n_0 * DIM + kb + 4]);
        float4 wa0 = *reinterpret_cast<const float4*>(&A[(size_t)n_1 * DIM + kb]);
        float4 wa1 = *reinterpret_cast<const float4*>(&A[(size_t)n_1 * DIM + kb + 4]);
        float4 wb0 = *reinterpret_cast<const float4*>(&B[(size_t)n_1 * DIM + kb]);
        float4 wb1 = *reinterpret_cast<const float4*>(&B[(size_t)n_1 * DIM + kb + 4]);
        va0.x *= invc0; va0.y *= invc0; va0.z *= invc0; va0.w *= invc0;
        va1.x *= invc0; va1.y *= invc0; va1.z *= invc0; va1.w *= invc0;
        wa0.x *= invc1; wa0.y *= invc1; wa0.z *= invc1; wa0.w *= invc1;
        wa1.x *= invc1; wa1.y *= invc1; wa1.z *= invc1; wa1.w *= invc1;
        if (bnB) {
            float4 sc0 = *reinterpret_cast<const float4*>(&bnsc[kb]);
            float4 sh0 = *reinterpret_cast<const float4*>(&bnsc[DIM + kb]);
            float4 sc1 = *reinterpret_cast<const float4*>(&bnsc[kb + 4]);
            float4 sh1 = *reinterpret_cast<const float4*>(&bnsc[DIM + kb + 4]);
            vb0.x = fmaxf(vb0.x * sc0.x + sh0.x, 0.f);
            vb0.y = fmaxf(vb0.y * sc0.y + sh0.y, 0.f);
            vb0.z = fmaxf(vb0.z * sc0.z + sh0.z, 0.f);
            vb0.w = fmaxf(vb0.w * sc0.w + sh0.w, 0.f);
            vb1.x = fmaxf(vb1.x * sc1.x + sh1.x, 0.f);
            vb1.y = fmaxf(vb1.y * sc1.y + sh1.y, 0.f);
            vb1.z = fmaxf(vb1.z * sc1.z + sh1.z, 0.f);
            vb1.w = fmaxf(vb1.w * sc1.w + sh1.w, 0.f);
            wb0.x = fmaxf(wb0.x * sc0.x + sh0.x, 0.f);
            wb0.y = fmaxf(wb0.y * sc0.y + sh0.y, 0.f);
            wb0.z = fmaxf(wb0.z * sc0.z + sh0.z, 0.f);
            wb0.w = fmaxf(wb0.w * sc0.w + sh0.w, 0.f);
            wb1.x = fmaxf(wb1.x * sc1.x + sh1.x, 0.f);
            wb1.y = fmaxf(wb1.y * sc1.y + sh1.y, 0.f);
            wb1.z = fmaxf(wb1.z * sc1.z + sh1.z, 0.f);
            wb1.w = fmaxf(wb1.w * sc1.w + sh1.w, 0.f);
        }
        s16x8 a0h, a0l, b0h, b0l, a1h, a1l, b1h, b1l;
        f2hl8(va0, va1, a0h, a0l);
        f2hl8(vb0, vb1, b0h, b0l);
        f2hl8(wa0, wa1, a1h, a1l);
        f2hl8(wb0, wb1, b1h, b1l);
        int fb = ks * 64 + l;
#pragma unroll
        for (int ct = 0; ct < 8; ++ct) {
            int fi = ct * 256 + fb;
            s16x8 wh1 = w1h[fi], wl1 = w1l[fi];
            s16x8 wh2 = w2h[fi], wl2 = w2l[fi];
            acc0[ct] = MFMA_BF16(a0h, wh1, acc0[ct], 0, 0, 0);
            acc0[ct] = MFMA_BF16(a0h, wl1, acc0[ct], 0, 0, 0);
            acc0[ct] = MFMA_BF16(a0l, wh1, acc0[ct], 0, 0, 0);
            acc0[ct] = MFMA_BF16(b0h, wh2, acc0[ct], 0, 0, 0);
            acc0[ct] = MFMA_BF16(b0h, wl2, acc0[ct], 0, 0, 0);
            acc0[ct] = MFMA_BF16(b0l, wh2, acc0[ct], 0, 0, 0);
            acc1[ct] = MFMA_BF16(a1h, wh1, acc1[ct], 0, 0, 0);
            acc1[ct] = MFMA_BF16(a1h, wl1, acc1[ct], 0, 0, 0);
            acc1[ct] = MFMA_BF16(a1l, wh1, acc1[ct], 0, 0, 0);
            acc1[ct] = MFMA_BF16(b1h, wh2, acc1[ct], 0, 0, 0);
            acc1[ct] = MFMA_BF16(b1h, wl2, acc1[ct], 0, 0, 0);
            acc1[ct] = MFMA_BF16(b1l, wh2, acc1[ct], 0, 0, 0);
        }
    }

    // ---- epilogue: bias, store, BN partial stats ----
    float p1s[8], p2s[8];
    int col0 = l & 15;
    int nb0 = n0 + w * 16 + (kh << 2);
    int nb1 = nb0 + 64;
#pragma unroll
    for (int ct = 0; ct < 8; ++ct) {
        float bj = bias[ct * 16 + col0];
        float s1 = 0.f, s2 = 0.f;
#pragma unroll
        for (int rr = 0; rr < 4; ++rr) {
            int n = nb0 + rr;
            float h = acc0[ct][rr] + bj;
            if (n < N_NODES) {
                OUT[(size_t)n * DIM + ct * 16 + col0] = h;
                s1 += h; s2 += h * h;
            }
            n = nb1 + rr;
            h = acc1[ct][rr] + bj;
            if (n < N_NODES) {
                OUT[(size_t)n * DIM + ct * 16 + col0] = h;
                s1 += h; s2 += h * h;
            }
        }
        p1s[ct] = s1; p2s[ct] = s2;
    }
    if (doBN) {
        __shared__ float red1[512];
        __shared__ float red2[512];
#pragma unroll
        for (int ct = 0; ct < 8; ++ct) {
            p1s[ct] += __shfl_xor(p1s[ct], 16);
            p1s[ct] += __shfl_xor(p1s[ct], 32);
            p2s[ct] += __shfl_xor(p2s[ct], 16);
            p2s[ct] += __shfl_xor(p2s[ct], 32);
        }
        if (l < 16) {
#pragma unroll
            for (int ct = 0; ct < 8; ++ct) {
                red1[w * 128 + ct * 16 + l] = p1s[ct];
                red2[w * 128 + ct * 16 + l] = p2s[ct];
            }
        }
        __syncthreads();
        if (t < 128) {
            float s1 = red1[t] + red1[128 + t] + red1[256 + t] + red1[384 + t];
            float s2 = red2[t] + red2[128 + t] + red2[256 + t] + red2[384 + t];
            atomicAdd(&bnacc[t], s1);
            atomicAdd(&bnacc[128 + t], s2);
        }
    }
}

// ---------------- BN finalize: scale/shift vector ----------------
__global__ void k_bnfinal(const float* __restrict__ bnacc, const float* __restrict__ gamma,
                          const float* __restrict__ beta, float* __restrict__ bnsc) {
    int d = threadIdx.x;
    if (d < DIM) {
        float mu = bnacc[d] / (float)N_NODES;
        float var = bnacc[128 + d] / (float)N_NODES - mu * mu;
        float rstd = rsqrtf(var + BN_EPS);
        float sc = gamma[d] * rstd;
        bnsc[d] = sc;
        bnsc[128 + d] = beta[d] - mu * sc;
    }
}

// ---------------- graph mean pool (batch is sorted), 4 slices ----------------
__global__ void k_pool(const float* __restrict__ H1, const int* __restrict__ batch,
                       float* __restrict__ gout) {
    __shared__ float red[4][128];
    int g = blockIdx.x;
    int t = threadIdx.x;
    int d = t & 127;
    int sl = t >> 7;
    int lo = 0, hi = N_NODES;
    while (lo < hi) { int m = (lo + hi) >> 1; if (batch[m] < g) lo = m + 1; else hi = m; }
    int s = lo;
    lo = 0; hi = N_NODES;
    while (lo < hi) { int m = (lo + hi) >> 1; if (batch[m] < g + 1) lo = m + 1; else hi = m; }
    int e = lo;
    float sum = 0.f;
    for (int n = s + sl; n < e; n += 4) sum += H1[(size_t)n * DIM + d];
    red[sl][d] = sum;
    __syncthreads();
    if (t < 128) {
        float tot = red[0][d] + red[1][d] + red[2][d] + red[3][d];
        gout[g * DIM + d] = tot / (float)max(e - s, 1);
    }
}

// ---------------- MFMA projection (no LDS, 2 strips/wave) --------------------
__global__ __launch_bounds__(256) void k_proj(
        const float* __restrict__ H1, const short* __restrict__ fWph,
        const short* __restrict__ fWpl, const float* __restrict__ bp,
        float* __restrict__ OUT) {
    int t = threadIdx.x, w = t >> 6, l = t & 63;
    int n0 = blockIdx.x * 128;
    int r = l & 15, kh = l >> 4;
    int row0 = n0 + w * 16 + r;
    int row1 = row0 + 64;
    int n_0 = min(row0, N_NODES - 1);
    int n_1 = min(row1, N_NODES - 1);
    f32x4 acc0[4], acc1[4];
#pragma unroll
    for (int ct = 0; ct < 4; ++ct) {
        acc0[ct] = (f32x4){0.f, 0.f, 0.f, 0.f};
        acc1[ct] = (f32x4){0.f, 0.f, 0.f, 0.f};
    }
    const s16x8* wph = (const s16x8*)fWph;
    const s16x8* wpl = (const s16x8*)fWpl;
#pragma unroll
    for (int ks = 0; ks < 4; ++ks) {
        int kb = ks * 32 + kh * 8;
        float4 va0 = relu4(*reinterpret_cast<const float4*>(&H1[(size_t)n_0 * DIM + kb]));
        float4 va1 = relu4(*reinterpret_cast<const float4*>(&H1[(size_t)n_0 * DIM + kb + 4]));
        float4 wa0 = relu4(*reinterpret_cast<const float4*>(&H1[(size_t)n_1 * DIM + kb]));
        float4 wa1 = relu4(*reinterpret_cast<const float4*>(&H1[(size_t)n_1 * DIM + kb + 4]));
        s16x8 a0h, a0l, a1h, a1l;
        f2hl8(va0, va1, a0h, a0l);
        f2hl8(wa0, wa1, a1h, a1l);
        int fb = ks * 64 + l;
#pragma unroll
        for (int ct = 0; ct < 4; ++ct) {
            int fi = ct * 256 + fb;
            s16x8 wh = wph[fi], wl = wpl[fi];
            acc0[ct] = MFMA_BF16(a0h, wh, acc0[ct], 0, 0, 0);
            acc0[ct] = MFMA_BF16(a0h, wl, acc0[ct], 0, 0, 0);
            acc0[ct] = MFMA_BF16(a0l, wh, acc0[ct], 0, 0, 0);
            acc1[ct] = MFMA_BF16(a1h, wh, acc1[ct], 0, 0, 0);
            acc1[ct] = MFMA_BF16(a1h, wl, acc1[ct], 0, 0, 0);
            acc1[ct] = MFMA_BF16(a1l, wh, acc1[ct], 0, 0, 0);
        }
    }
    int col0 = l & 15;
    int nb0 = n0 + w * 16 + (kh << 2);
    int nb1 = nb0 + 64;
#pragma unroll
    for (int ct = 0; ct < 4; ++ct) {
        float bj = bp[ct * 16 + col0];
#pragma unroll
        for (int rr = 0; rr < 4; ++rr) {
            int n = nb0 + rr;
            if (n < N_NODES)
                OUT[(size_t)n * NCLS + ct * 16 + col0] = acc0[ct][rr] + bj;
            n = nb1 + rr;
            if (n < N_NODES)
                OUT[(size_t)n * NCLS + ct * 16 + col0] = acc1[ct][rr] + bj;
        }
    }
}

extern "C" void kernel_launch(void* const* d_in, const int* in_sizes, int n_in,
                              void* d_out, int out_size, void* d_ws, size_t ws_size,
                              hipStream_t stream) {
    (void)in_sizes; (void)n_in; (void)out_size; (void)ws_size;
    const float* x     = (const float*)d_in[0];
    const float* xe    = (const float*)d_in[1];
    const int*   eidx  = (const int*)d_in[2];
    const int*   batch = (const int*)d_in[3];
    const float* Wl0   = (const float*)d_in[4];
    const float* bl0   = (const float*)d_in[5];
    const float* Wr0   = (const float*)d_in[6];
    const float* Wl1   = (const float*)d_in[7];
    const float* bl1   = (const float*)d_in[8];
    const float* Wr1   = (const float*)d_in[9];
    const float* gamma0 = (const float*)d_in[10];
    const float* beta0  = (const float*)d_in[11];
    const float* Wp    = (const float*)d_in[12];
    const float* bp    = (const float*)d_in[13];
    const int* srcp = eidx;
    const int* dstp = eidx + N_EDGES;

    char* ws = (char*)d_ws;
    size_t off = 0;
    auto carve = [&](size_t bytes) {
        void* p = ws + off;
        off = (off + bytes + 255) & ~(size_t)255;
        return p;
    };
    int*   cnt    = (int*)carve((size_t)N_NODES * 4);
    float* bnacc  = (float*)carve(256 * 4);
    float* bnsc   = (float*)carve(256 * 4);
    float* AGG0   = (float*)carve((size_t)2 * N_NODES * DIM * 4);  // AGG0 | AGG1 contiguous
    float* AGG1   = AGG0 + (size_t)N_NODES * DIM;
    float* H      = (float*)carve((size_t)N_NODES * DIM * 4);
    float* H1     = (float*)carve((size_t)N_NODES * DIM * 4);
    short* fWl0h = (short*)carve(16384 * 2);
    short* fWl0l = (short*)carve(16384 * 2);
    short* fWr0h = (short*)carve(16384 * 2);
    short* fWr0l = (short*)carve(16384 * 2);
    short* fWl1h = (short*)carve(16384 * 2);
    short* fWl1l = (short*)carve(16384 * 2);
    short* fWr1h = (short*)carve(16384 * 2);
    short* fWr1l = (short*)carve(16384 * 2);
    short* fWph  = (short*)carve(8192 * 2);
    short* fWpl  = (short*)carve(8192 * 2);

    float* out_h = (float*)d_out;
    float* out_g = out_h + (size_t)N_NODES * NCLS;

    hipMemsetAsync(AGG0, 0, (size_t)2 * N_NODES * DIM * 4, stream);
    hipMemsetAsync(cnt, 0, (size_t)N_NODES * 4, stream);
    hipMemsetAsync(bnacc, 0, 256 * 4, stream);

    k_wprep_all<<<36, 256, 0, stream>>>(Wl0, Wr0, Wl1, Wr1, Wp,
                                        fWl0h, fWl0l, fWr0h, fWr0l,
                                        fWl1h, fWl1l, fWr1h, fWr1l,
                                        fWph, fWpl);

    int sblocks = N_EDGES / 8;            // 2 edges/wave, 4 waves/block
    int gblocks = (N_NODES + 127) / 128;  // 782

    // layer 0: edge-order scatter (+degree count) -> dual GEMM (+BN stats)
    k_scat<<<sblocks, 256, 0, stream>>>(x, xe, srcp, dstp, AGG0, cnt, bnsc, 0, 1);
    k_gemm2<<<gblocks, 256, 0, stream>>>(AGG0, x, cnt, fWl0h, fWl0l, fWr0h, fWr0l,
                                         bl0, H, bnacc, bnsc, 1, 0);
    k_bnfinal<<<1, 128, 0, stream>>>(bnacc, gamma0, beta0, bnsc);

    // layer 1: scatter with BN+relu applied to gathered H
    k_scat<<<sblocks, 256, 0, stream>>>(H, xe, srcp, dstp, AGG1, cnt, bnsc, 1, 0);
    k_gemm2<<<gblocks, 256, 0, stream>>>(AGG1, H, cnt, fWl1h, fWl1l, fWr1h, fWr1l,
                                         bl1, H1, bnacc, bnsc, 0, 1);

    // readout
    k_pool<<<NG, 512, 0, stream>>>(H1, batch, out_g);
    k_proj<<<gblocks, 256, 0, stream>>>(H1, fWph, fWpl, bp, out_h);
}

// Round 7
// 945.700 us; speedup vs baseline: 6.0567x; 6.0567x over previous
//
#include <hip/hip_runtime.h>

#define N_NODES 100000
#define N_EDGES 1600000
#define DIM 128
#define NCLS 64
#define NG 128
#define BN_EPS 1e-5f

typedef __attribute__((ext_vector_type(8))) short s16x8;
typedef __attribute__((ext_vector_type(4))) float f32x4;
#define MFMA_BF16 __builtin_amdgcn_mfma_f32_16x16x32_bf16

// f32 -> bf16 RNE
__device__ __forceinline__ unsigned short f2b(float x) {
    unsigned u = __float_as_uint(x);
    return (unsigned short)((u + 0x7FFFu + ((u >> 16) & 1u)) >> 16);
}
__device__ __forceinline__ float b2f(unsigned short s) {
    return __uint_as_float(((unsigned)s) << 16);
}
__device__ __forceinline__ float4 bexp4(ushort4 u) {
    float4 f;
    f.x = b2f(u.x); f.y = b2f(u.y); f.z = b2f(u.z); f.w = b2f(u.w);
    return f;
}

// split 8 f32 into bf16 hi + bf16 lo (truncation; hi+lo ~exact to 2^-16 rel)
__device__ __forceinline__ void f2hl8(float4 v0, float4 v1, s16x8& h8, s16x8& l8) {
    float vv[8] = {v0.x, v0.y, v0.z, v0.w, v1.x, v1.y, v1.z, v1.w};
#pragma unroll
    for (int i = 0; i < 8; ++i) {
        unsigned u = __float_as_uint(vv[i]);
        short h = (short)(u >> 16);
        float r = vv[i] - __uint_as_float(u & 0xFFFF0000u);
        short l = (short)(__float_as_uint(r) >> 16);
        h8[i] = h;
        l8[i] = l;
    }
}

__device__ __forceinline__ float4 relu4(float4 v) {
    v.x = fmaxf(v.x, 0.f); v.y = fmaxf(v.y, 0.f);
    v.z = fmaxf(v.z, 0.f); v.w = fmaxf(v.w, 0.f);
    return v;
}

// ---------------- f32 -> bf16 buffer convert (x -> x_bf) ----------------
__global__ void k_cvt(const float* __restrict__ in, unsigned short* __restrict__ out,
                      int n8) {
    int i = blockIdx.x * 256 + threadIdx.x;
    if (i >= n8) return;
    float4 a = reinterpret_cast<const float4*>(in)[(size_t)i * 2];
    float4 b = reinterpret_cast<const float4*>(in)[(size_t)i * 2 + 1];
    ushort4 oa, ob;
    oa.x = f2b(a.x); oa.y = f2b(a.y); oa.z = f2b(a.z); oa.w = f2b(a.w);
    ob.x = f2b(b.x); ob.y = f2b(b.y); ob.z = f2b(b.z); ob.w = f2b(b.w);
    reinterpret_cast<ushort4*>(out)[(size_t)i * 2] = oa;
    reinterpret_cast<ushort4*>(out)[(size_t)i * 2 + 1] = ob;
}

// ---------------- degree histogram ----------------
__global__ void k_hist(const int* __restrict__ dst, int* __restrict__ cnt) {
    int e = blockIdx.x * 256 + threadIdx.x;
    if (e < N_EDGES) atomicAdd(&cnt[dst[e]], 1);
}

// ---------------- exclusive scan (3 kernels) ----------------
__global__ void k_scan1(const int* __restrict__ cnt, int* __restrict__ rowptr,
                        int* __restrict__ bsums) {
    __shared__ int sd[1024];
    int tid = threadIdx.x;
    int i = blockIdx.x * 1024 + tid;
    int v = (i < N_NODES) ? cnt[i] : 0;
    sd[tid] = v;
    __syncthreads();
    for (int off = 1; off < 1024; off <<= 1) {
        int t2 = (tid >= off) ? sd[tid - off] : 0;
        __syncthreads();
        sd[tid] += t2;
        __syncthreads();
    }
    if (i < N_NODES) rowptr[i] = sd[tid] - v;
    if (tid == 1023) bsums[blockIdx.x] = sd[tid];
}

__global__ void k_scan2(int* __restrict__ bsums, int nb) {
    __shared__ int sd[128];
    int t = threadIdx.x;
    int v = (t < nb) ? bsums[t] : 0;
    sd[t] = v;
    __syncthreads();
    for (int off = 1; off < 128; off <<= 1) {
        int u = (t >= off) ? sd[t - off] : 0;
        __syncthreads();
        sd[t] += u;
        __syncthreads();
    }
    if (t < nb) bsums[t] = sd[t] - v;
}

__global__ void k_scan3(int* __restrict__ rowptr, const int* __restrict__ bsums,
                        int* __restrict__ wcur) {
    int i = blockIdx.x * 1024 + threadIdx.x;
    if (i < N_NODES) {
        int v = rowptr[i] + bsums[blockIdx.x];
        rowptr[i] = v;
        wcur[i] = v;
    }
    if (i == N_NODES - 1) rowptr[N_NODES] = N_EDGES;
}

// ---------------- bucket edges by dst; optionally permute+compress xe --------
// One wave = 2 edges (half-wave each). PACK: also write xe row (bf16) to xe_s[p].
template <int PACK>
__global__ __launch_bounds__(256) void k_scatter(
        const int* __restrict__ src, const int* __restrict__ dst,
        int* __restrict__ wcur, int2* __restrict__ esort,
        const float* __restrict__ xe, unsigned short* __restrict__ xe_s) {
    int wid = (blockIdx.x * 256 + threadIdx.x) >> 6;
    int lane = threadIdx.x & 63;
    int half = lane >> 5, l = lane & 31;
    long e = (long)wid * 2 + half;
    if (e >= N_EDGES) return;
    int s = src[e], d = dst[e];
    int p0 = 0;
    if (l == 0) p0 = atomicAdd(&wcur[d], 1);
    int p = __shfl(p0, half * 32);
    if (l == 0) esort[p] = make_int2((int)e, s);
    if (PACK) {
        float4 v = *reinterpret_cast<const float4*>(&xe[(size_t)e * DIM + l * 4]);
        ushort4 o;
        o.x = f2b(v.x); o.y = f2b(v.y); o.z = f2b(v.z); o.w = f2b(v.w);
        *reinterpret_cast<ushort4*>(&xe_s[(size_t)p * DIM + l * 4]) = o;
    }
}

// ---------------- gather-aggregate: one wave/node, 4 edges/half-wave --------
// XES=1: xe_s bf16 permuted (sequential). XES=0: xe f32 via esort.x (random).
template <int XES>
__global__ __launch_bounds__(256) void k_agg(
        const unsigned short* __restrict__ Fb, const float* __restrict__ xe,
        const unsigned short* __restrict__ xe_s,
        const int* __restrict__ rowptr, const int2* __restrict__ esort,
        float* __restrict__ agg, const float* __restrict__ bnsc, int applyBN) {
    int wid = (blockIdx.x * 256 + threadIdx.x) >> 6;
    int lane = threadIdx.x & 63;
    if (wid >= N_NODES) return;
    int half = lane >> 5;
    int l = lane & 31;
    int p0 = rowptr[wid], p1 = rowptr[wid + 1];
    if (p0 == p1) {
        if (half == 0) {
            float4 z = make_float4(0.f, 0.f, 0.f, 0.f);
            *reinterpret_cast<float4*>(&agg[(size_t)wid * DIM + l * 4]) = z;
        }
        return;
    }
    float4 sc, sh;
    if (applyBN) {
        sc = *reinterpret_cast<const float4*>(&bnsc[l * 4]);
        sh = *reinterpret_cast<const float4*>(&bnsc[DIM + l * 4]);
    }
    float4 acc = make_float4(0.f, 0.f, 0.f, 0.f);
    for (int p = p0; p < p1; p += 8) {
#pragma unroll
        for (int j = 0; j < 4; ++j) {
            int q = p + j * 2 + half;
            int qc = min(q, p1 - 1);
            int2 es = esort[qc];
            float4 a = bexp4(*reinterpret_cast<const ushort4*>(
                &Fb[(size_t)es.y * DIM + l * 4]));
            float4 b;
            if (XES) {
                b = bexp4(*reinterpret_cast<const ushort4*>(
                    &xe_s[(size_t)qc * DIM + l * 4]));
            } else {
                b = *reinterpret_cast<const float4*>(
                    &xe[(size_t)es.x * DIM + l * 4]);
            }
            if (applyBN) {
                a.x = fmaxf(a.x * sc.x + sh.x, 0.f);
                a.y = fmaxf(a.y * sc.y + sh.y, 0.f);
                a.z = fmaxf(a.z * sc.z + sh.z, 0.f);
                a.w = fmaxf(a.w * sc.w + sh.w, 0.f);
            }
            if (q < p1) {
                acc.x += fmaxf(a.x + b.x, 0.f);
                acc.y += fmaxf(a.y + b.y, 0.f);
                acc.z += fmaxf(a.z + b.z, 0.f);
                acc.w += fmaxf(a.w + b.w, 0.f);
            }
        }
    }
    acc.x += __shfl_xor(acc.x, 32);
    acc.y += __shfl_xor(acc.y, 32);
    acc.z += __shfl_xor(acc.z, 32);
    acc.w += __shfl_xor(acc.w, 32);
    if (half == 0) {
        float s = 1.f / (float)(p1 - p0);
        acc.x *= s; acc.y *= s; acc.z *= s; acc.w *= s;
        *reinterpret_cast<float4*>(&agg[(size_t)wid * DIM + l * 4]) = acc;
    }
}

// ---------------- weight prep (ALL matrices in one launch) ----------------
__global__ void k_wprep_all(const float* __restrict__ Wl0, const float* __restrict__ Wr0,
                            const float* __restrict__ Wl1, const float* __restrict__ Wr1,
                            const float* __restrict__ Wp,
                            short* __restrict__ fWl0h, short* __restrict__ fWl0l,
                            short* __restrict__ fWr0h, short* __restrict__ fWr0l,
                            short* __restrict__ fWl1h, short* __restrict__ fWl1l,
                            short* __restrict__ fWr1h, short* __restrict__ fWr1l,
                            short* __restrict__ fWph, short* __restrict__ fWpl) {
    int b = blockIdx.x;          // 0..35
    const float* W; short* hi; short* lo; int ct;
    if (b < 8)       { W = Wl0; hi = fWl0h; lo = fWl0l; ct = b; }
    else if (b < 16) { W = Wr0; hi = fWr0h; lo = fWr0l; ct = b - 8; }
    else if (b < 24) { W = Wl1; hi = fWl1h; lo = fWl1l; ct = b - 16; }
    else if (b < 32) { W = Wr1; hi = fWr1h; lo = fWr1l; ct = b - 24; }
    else             { W = Wp;  hi = fWph;  lo = fWpl;  ct = b - 32; }
    int tt = threadIdx.x;
    int lane = tt & 63, ks = (tt >> 6) & 3;
    int row = ct * 16 + (lane & 15);
    int k0 = ks * 32 + ((lane >> 4) << 3);
    float4 v0 = *reinterpret_cast<const float4*>(&W[(size_t)row * DIM + k0]);
    float4 v1 = *reinterpret_cast<const float4*>(&W[(size_t)row * DIM + k0 + 4]);
    s16x8 h8, l8;
    f2hl8(v0, v1, h8, l8);
    int t = ct * 256 + ks * 64 + lane;
    *reinterpret_cast<s16x8*>(&hi[(size_t)t * 8]) = h8;
    *reinterpret_cast<s16x8*>(&lo[(size_t)t * 8]) = l8;
}

// ---------------- MFMA dual GEMM: OUT = A@W1^T + bn?(Bbf)@W2^T + bias --------
// A f32 (hi/lo split, 3 MFMA); B bf16 (2 MFMA). 2 strips/wave, 128 nodes/block.
// OUTb != nullptr -> write bf16; else write f32 to OUTf.
__global__ __launch_bounds__(256) void k_gemm2(
        const float* __restrict__ A, const unsigned short* __restrict__ Bbf,
        const short* __restrict__ fW1h, const short* __restrict__ fW1l,
        const short* __restrict__ fW2h, const short* __restrict__ fW2l,
        const float* __restrict__ bias, float* __restrict__ OUTf,
        unsigned short* __restrict__ OUTb,
        float* __restrict__ bnacc, const float* __restrict__ bnsc,
        int doBN, int bnB) {
    int t = threadIdx.x, w = t >> 6, l = t & 63;
    int n0 = blockIdx.x * 128;
    int r = l & 15, kh = l >> 4;
    int row0 = n0 + w * 16 + r;
    int row1 = row0 + 64;
    int n_0 = min(row0, N_NODES - 1);
    int n_1 = min(row1, N_NODES - 1);

    f32x4 acc0[8], acc1[8];
#pragma unroll
    for (int ct = 0; ct < 8; ++ct) {
        acc0[ct] = (f32x4){0.f, 0.f, 0.f, 0.f};
        acc1[ct] = (f32x4){0.f, 0.f, 0.f, 0.f};
    }
    const s16x8* w1h = (const s16x8*)fW1h;
    const s16x8* w1l = (const s16x8*)fW1l;
    const s16x8* w2h = (const s16x8*)fW2h;
    const s16x8* w2l = (const s16x8*)fW2l;

#pragma unroll
    for (int ks = 0; ks < 4; ++ks) {
        int kb = ks * 32 + kh * 8;
        float4 va0 = *reinterpret_cast<const float4*>(&A[(size_t)n_0 * DIM + kb]);
        float4 va1 = *reinterpret_cast<const float4*>(&A[(size_t)n_0 * DIM + kb + 4]);
        float4 wa0 = *reinterpret_cast<const float4*>(&A[(size_t)n_1 * DIM + kb]);
        float4 wa1 = *reinterpret_cast<const float4*>(&A[(size_t)n_1 * DIM + kb + 4]);
        s16x8 b0 = *reinterpret_cast<const s16x8*>(&Bbf[(size_t)n_0 * DIM + kb]);
        s16x8 b1 = *reinterpret_cast<const s16x8*>(&Bbf[(size_t)n_1 * DIM + kb]);
        if (bnB) {
            float4 sc0 = *reinterpret_cast<const float4*>(&bnsc[kb]);
            float4 sh0 = *reinterpret_cast<const float4*>(&bnsc[DIM + kb]);
            float4 sc1 = *reinterpret_cast<const float4*>(&bnsc[kb + 4]);
            float4 sh1 = *reinterpret_cast<const float4*>(&bnsc[DIM + kb + 4]);
            float scv[8] = {sc0.x, sc0.y, sc0.z, sc0.w, sc1.x, sc1.y, sc1.z, sc1.w};
            float shv[8] = {sh0.x, sh0.y, sh0.z, sh0.w, sh1.x, sh1.y, sh1.z, sh1.w};
#pragma unroll
            for (int i = 0; i < 8; ++i) {
                float v = b2f((unsigned short)b0[i]);
                b0[i] = (short)f2b(fmaxf(v * scv[i] + shv[i], 0.f));
                v = b2f((unsigned short)b1[i]);
                b1[i] = (short)f2b(fmaxf(v * scv[i] + shv[i], 0.f));
            }
        }
        s16x8 a0h, a0l, a1h, a1l;
        f2hl8(va0, va1, a0h, a0l);
        f2hl8(wa0, wa1, a1h, a1l);
        int fb = ks * 64 + l;
#pragma unroll
        for (int ct = 0; ct < 8; ++ct) {
            int fi = ct * 256 + fb;
            s16x8 wh1 = w1h[fi], wl1 = w1l[fi];
            s16x8 wh2 = w2h[fi], wl2 = w2l[fi];
            acc0[ct] = MFMA_BF16(a0h, wh1, acc0[ct], 0, 0, 0);
            acc0[ct] = MFMA_BF16(a0h, wl1, acc0[ct], 0, 0, 0);
            acc0[ct] = MFMA_BF16(a0l, wh1, acc0[ct], 0, 0, 0);
            acc0[ct] = MFMA_BF16(b0, wh2, acc0[ct], 0, 0, 0);
            acc0[ct] = MFMA_BF16(b0, wl2, acc0[ct], 0, 0, 0);
            acc1[ct] = MFMA_BF16(a1h, wh1, acc1[ct], 0, 0, 0);
            acc1[ct] = MFMA_BF16(a1h, wl1, acc1[ct], 0, 0, 0);
            acc1[ct] = MFMA_BF16(a1l, wh1, acc1[ct], 0, 0, 0);
            acc1[ct] = MFMA_BF16(b1, wh2, acc1[ct], 0, 0, 0);
            acc1[ct] = MFMA_BF16(b1, wl2, acc1[ct], 0, 0, 0);
        }
    }

    // ---- epilogue: bias, store, BN partial stats ----
    float p1s[8], p2s[8];
    int col0 = l & 15;
    int nb0 = n0 + w * 16 + (kh << 2);
    int nb1 = nb0 + 64;
#pragma unroll
    for (int ct = 0; ct < 8; ++ct) {
        float bj = bias[ct * 16 + col0];
        float s1 = 0.f, s2 = 0.f;
#pragma unroll
        for (int rr = 0; rr < 4; ++rr) {
            int n = nb0 + rr;
            float h = acc0[ct][rr] + bj;
            if (n < N_NODES) {
                if (OUTb) OUTb[(size_t)n * DIM + ct * 16 + col0] = f2b(h);
                else      OUTf[(size_t)n * DIM + ct * 16 + col0] = h;
                s1 += h; s2 += h * h;
            }
            n = nb1 + rr;
            h = acc1[ct][rr] + bj;
            if (n < N_NODES) {
                if (OUTb) OUTb[(size_t)n * DIM + ct * 16 + col0] = f2b(h);
                else      OUTf[(size_t)n * DIM + ct * 16 + col0] = h;
                s1 += h; s2 += h * h;
            }
        }
        p1s[ct] = s1; p2s[ct] = s2;
    }
    if (doBN) {
        __shared__ float red1[512];
        __shared__ float red2[512];
#pragma unroll
        for (int ct = 0; ct < 8; ++ct) {
            p1s[ct] += __shfl_xor(p1s[ct], 16);
            p1s[ct] += __shfl_xor(p1s[ct], 32);
            p2s[ct] += __shfl_xor(p2s[ct], 16);
            p2s[ct] += __shfl_xor(p2s[ct], 32);
        }
        if (l < 16) {
#pragma unroll
            for (int ct = 0; ct < 8; ++ct) {
                red1[w * 128 + ct * 16 + l] = p1s[ct];
                red2[w * 128 + ct * 16 + l] = p2s[ct];
            }
        }
        __syncthreads();
        if (t < 128) {
            float s1 = red1[t] + red1[128 + t] + red1[256 + t] + red1[384 + t];
            float s2 = red2[t] + red2[128 + t] + red2[256 + t] + red2[384 + t];
            atomicAdd(&bnacc[t], s1);
            atomicAdd(&bnacc[128 + t], s2);
        }
    }
}

// ---------------- BN finalize: scale/shift vector ----------------
__global__ void k_bnfinal(const float* __restrict__ bnacc, const float* __restrict__ gamma,
                          const float* __restrict__ beta, float* __restrict__ bnsc) {
    int d = threadIdx.x;
    if (d < DIM) {
        float mu = bnacc[d] / (float)N_NODES;
        float var = bnacc[128 + d] / (float)N_NODES - mu * mu;
        float rstd = rsqrtf(var + BN_EPS);
        float sc = gamma[d] * rstd;
        bnsc[d] = sc;
        bnsc[128 + d] = beta[d] - mu * sc;
    }
}

// ---------------- graph mean pool (batch is sorted), 4 slices ----------------
__global__ void k_pool(const float* __restrict__ H1, const int* __restrict__ batch,
                       float* __restrict__ gout) {
    __shared__ float red[4][128];
    int g = blockIdx.x;
    int t = threadIdx.x;
    int d = t & 127;
    int sl = t >> 7;
    int lo = 0, hi = N_NODES;
    while (lo < hi) { int m = (lo + hi) >> 1; if (batch[m] < g) lo = m + 1; else hi = m; }
    int s = lo;
    lo = 0; hi = N_NODES;
    while (lo < hi) { int m = (lo + hi) >> 1; if (batch[m] < g + 1) lo = m + 1; else hi = m; }
    int e = lo;
    float sum = 0.f;
    for (int n = s + sl; n < e; n += 4) sum += H1[(size_t)n * DIM + d];
    red[sl][d] = sum;
    __syncthreads();
    if (t < 128) {
        float tot = red[0][d] + red[1][d] + red[2][d] + red[3][d];
        gout[g * DIM + d] = tot / (float)max(e - s, 1);
    }
}

// ---------------- MFMA projection (no LDS, 2 strips/wave) --------------------
__global__ __launch_bounds__(256) void k_proj(
        const float* __restrict__ H1, const short* __restrict__ fWph,
        const short* __restrict__ fWpl, const float* __restrict__ bp,
        float* __restrict__ OUT) {
    int t = threadIdx.x, w = t >> 6, l = t & 63;
    int n0 = blockIdx.x * 128;
    int r = l & 15, kh = l >> 4;
    int row0 = n0 + w * 16 + r;
    int row1 = row0 + 64;
    int n_0 = min(row0, N_NODES - 1);
    int n_1 = min(row1, N_NODES - 1);
    f32x4 acc0[4], acc1[4];
#pragma unroll
    for (int ct = 0; ct < 4; ++ct) {
        acc0[ct] = (f32x4){0.f, 0.f, 0.f, 0.f};
        acc1[ct] = (f32x4){0.f, 0.f, 0.f, 0.f};
    }
    const s16x8* wph = (const s16x8*)fWph;
    const s16x8* wpl = (const s16x8*)fWpl;
#pragma unroll
    for (int ks = 0; ks < 4; ++ks) {
        int kb = ks * 32 + kh * 8;
        float4 va0 = relu4(*reinterpret_cast<const float4*>(&H1[(size_t)n_0 * DIM + kb]));
        float4 va1 = relu4(*reinterpret_cast<const float4*>(&H1[(size_t)n_0 * DIM + kb + 4]));
        float4 wa0 = relu4(*reinterpret_cast<const float4*>(&H1[(size_t)n_1 * DIM + kb]));
        float4 wa1 = relu4(*reinterpret_cast<const float4*>(&H1[(size_t)n_1 * DIM + kb + 4]));
        s16x8 a0h, a0l, a1h, a1l;
        f2hl8(va0, va1, a0h, a0l);
        f2hl8(wa0, wa1, a1h, a1l);
        int fb = ks * 64 + l;
#pragma unroll
        for (int ct = 0; ct < 4; ++ct) {
            int fi = ct * 256 + fb;
            s16x8 wh = wph[fi], wl = wpl[fi];
            acc0[ct] = MFMA_BF16(a0h, wh, acc0[ct], 0, 0, 0);
            acc0[ct] = MFMA_BF16(a0h, wl, acc0[ct], 0, 0, 0);
            acc0[ct] = MFMA_BF16(a0l, wh, acc0[ct], 0, 0, 0);
            acc1[ct] = MFMA_BF16(a1h, wh, acc1[ct], 0, 0, 0);
            acc1[ct] = MFMA_BF16(a1h, wl, acc1[ct], 0, 0, 0);
            acc1[ct] = MFMA_BF16(a1l, wh, acc1[ct], 0, 0, 0);
        }
    }
    int col0 = l & 15;
    int nb0 = n0 + w * 16 + (kh << 2);
    int nb1 = nb0 + 64;
#pragma unroll
    for (int ct = 0; ct < 4; ++ct) {
        float bj = bp[ct * 16 + col0];
#pragma unroll
        for (int rr = 0; rr < 4; ++rr) {
            int n = nb0 + rr;
            if (n < N_NODES)
                OUT[(size_t)n * NCLS + ct * 16 + col0] = acc0[ct][rr] + bj;
            n = nb1 + rr;
            if (n < N_NODES)
                OUT[(size_t)n * NCLS + ct * 16 + col0] = acc1[ct][rr] + bj;
        }
    }
}

extern "C" void kernel_launch(void* const* d_in, const int* in_sizes, int n_in,
                              void* d_out, int out_size, void* d_ws, size_t ws_size,
                              hipStream_t stream) {
    (void)in_sizes; (void)n_in; (void)out_size;
    const float* x     = (const float*)d_in[0];
    const float* xe    = (const float*)d_in[1];
    const int*   eidx  = (const int*)d_in[2];
    const int*   batch = (const int*)d_in[3];
    const float* Wl0   = (const float*)d_in[4];
    const float* bl0   = (const float*)d_in[5];
    const float* Wr0   = (const float*)d_in[6];
    const float* Wl1   = (const float*)d_in[7];
    const float* bl1   = (const float*)d_in[8];
    const float* Wr1   = (const float*)d_in[9];
    const float* gamma0 = (const float*)d_in[10];
    const float* beta0  = (const float*)d_in[11];
    const float* Wp    = (const float*)d_in[12];
    const float* bp    = (const float*)d_in[13];
    const int* srcp = eidx;
    const int* dstp = eidx + N_EDGES;

    char* ws = (char*)d_ws;
    size_t off = 0;
    auto carve = [&](size_t bytes) {
        void* p = ws + off;
        off = (off + bytes + 255) & ~(size_t)255;
        return p;
    };
    int*   cnt    = (int*)carve((size_t)N_NODES * 4);
    int*   rowptr = (int*)carve((size_t)(N_NODES + 1) * 4);
    int*   wcur   = (int*)carve((size_t)N_NODES * 4);
    int*   bsums  = (int*)carve(128 * 4);
    float* bnacc  = (float*)carve(256 * 4);
    float* bnsc   = (float*)carve(256 * 4);
    int2*  esort  = (int2*)carve((size_t)N_EDGES * 8);
    float* AGG    = (float*)carve((size_t)N_NODES * DIM * 4);
    float* H1     = (float*)carve((size_t)N_NODES * DIM * 4);
    unsigned short* x_bf = (unsigned short*)carve((size_t)N_NODES * DIM * 2);
    unsigned short* H_bf = (unsigned short*)carve((size_t)N_NODES * DIM * 2);
    short* fWl0h = (short*)carve(16384 * 2);
    short* fWl0l = (short*)carve(16384 * 2);
    short* fWr0h = (short*)carve(16384 * 2);
    short* fWr0l = (short*)carve(16384 * 2);
    short* fWl1h = (short*)carve(16384 * 2);
    short* fWl1l = (short*)carve(16384 * 2);
    short* fWr1h = (short*)carve(16384 * 2);
    short* fWr1l = (short*)carve(16384 * 2);
    short* fWph  = (short*)carve(8192 * 2);
    short* fWpl  = (short*)carve(8192 * 2);

    // xe_s (permuted bf16 edge features) carved last; only if workspace allows
    size_t xes_bytes = (size_t)N_EDGES * DIM * 2;   // 409.6 MB
    int pack = (off + xes_bytes + 256 <= ws_size) ? 1 : 0;
    unsigned short* xe_s = pack ? (unsigned short*)carve(xes_bytes) : nullptr;

    float* out_h = (float*)d_out;
    float* out_g = out_h + (size_t)N_NODES * NCLS;

    hipMemsetAsync(cnt, 0, (size_t)N_NODES * 4, stream);
    hipMemsetAsync(bnacc, 0, 256 * 4, stream);

    k_wprep_all<<<36, 256, 0, stream>>>(Wl0, Wr0, Wl1, Wr1, Wp,
                                        fWl0h, fWl0l, fWr0h, fWr0l,
                                        fWl1h, fWl1l, fWr1h, fWr1l,
                                        fWph, fWpl);
    k_cvt<<<(N_NODES * DIM / 8 + 255) / 256, 256, 0, stream>>>(x, x_bf,
                                                               N_NODES * DIM / 8);

    int nb = (N_NODES + 1023) / 1024;  // 98
    k_hist<<<(N_EDGES + 255) / 256, 256, 0, stream>>>(dstp, cnt);
    k_scan1<<<nb, 1024, 0, stream>>>(cnt, rowptr, bsums);
    k_scan2<<<1, 128, 0, stream>>>(bsums, nb);
    k_scan3<<<nb, 1024, 0, stream>>>(rowptr, bsums, wcur);
    if (pack)
        k_scatter<1><<<N_EDGES / 8, 256, 0, stream>>>(srcp, dstp, wcur, esort, xe, xe_s);
    else
        k_scatter<0><<<N_EDGES / 8, 256, 0, stream>>>(srcp, dstp, wcur, esort, xe, nullptr);

    int ablocks = (N_NODES * 64 + 255) / 256;
    int gblocks = (N_NODES + 127) / 128;  // 782

    // layer 0
    if (pack)
        k_agg<1><<<ablocks, 256, 0, stream>>>(x_bf, xe, xe_s, rowptr, esort, AGG, bnsc, 0);
    else
        k_agg<0><<<ablocks, 256, 0, stream>>>(x_bf, xe, nullptr, rowptr, esort, AGG, bnsc, 0);
    k_gemm2<<<gblocks, 256, 0, stream>>>(AGG, x_bf, fWl0h, fWl0l, fWr0h, fWr0l,
                                         bl0, nullptr, H_bf, bnacc, bnsc, 1, 0);
    k_bnfinal<<<1, 128, 0, stream>>>(bnacc, gamma0, beta0, bnsc);

    // layer 1 (BN+relu fused into consumers)
    if (pack)
        k_agg<1><<<ablocks, 256, 0, stream>>>(H_bf, xe, xe_s, rowptr, esort, AGG, bnsc, 1);
    else
        k_agg<0><<<ablocks, 256, 0, stream>>>(H_bf, xe, nullptr, rowptr, esort, AGG, bnsc, 1);
    k_gemm2<<<gblocks, 256, 0, stream>>>(AGG, H_bf, fWl1h, fWl1l, fWr1h, fWr1l,
                                         bl1, H1, nullptr, bnacc, bnsc, 0, 1);

    // readout
    k_pool<<<NG, 512, 0, stream>>>(H1, batch, out_g);
    k_proj<<<gblocks, 256, 0, stream>>>(H1, fWph, fWpl, bp, out_h);
}

// Round 8
// 866.125 us; speedup vs baseline: 6.6132x; 1.0919x over previous
//
#include <hip/hip_runtime.h>

#define N_NODES 100000
#define N_EDGES 1600000
#define DIM 128
#define NCLS 64
#define NG 128
#define BN_EPS 1e-5f

typedef __attribute__((ext_vector_type(8))) short s16x8;
typedef __attribute__((ext_vector_type(4))) float f32x4;
#define MFMA_BF16 __builtin_amdgcn_mfma_f32_16x16x32_bf16

// f32 -> bf16 RNE
__device__ __forceinline__ unsigned short f2b(float x) {
    unsigned u = __float_as_uint(x);
    return (unsigned short)((u + 0x7FFFu + ((u >> 16) & 1u)) >> 16);
}
__device__ __forceinline__ float b2f(unsigned short s) {
    return __uint_as_float(((unsigned)s) << 16);
}
__device__ __forceinline__ float4 bexp4(ushort4 u) {
    float4 f;
    f.x = b2f(u.x); f.y = b2f(u.y); f.z = b2f(u.z); f.w = b2f(u.w);
    return f;
}

// split 8 f32 into bf16 hi + bf16 lo (truncation; hi+lo ~exact to 2^-16 rel)
__device__ __forceinline__ void f2hl8(float4 v0, float4 v1, s16x8& h8, s16x8& l8) {
    float vv[8] = {v0.x, v0.y, v0.z, v0.w, v1.x, v1.y, v1.z, v1.w};
#pragma unroll
    for (int i = 0; i < 8; ++i) {
        unsigned u = __float_as_uint(vv[i]);
        short h = (short)(u >> 16);
        float r = vv[i] - __uint_as_float(u & 0xFFFF0000u);
        short l = (short)(__float_as_uint(r) >> 16);
        h8[i] = h;
        l8[i] = l;
    }
}

__device__ __forceinline__ float4 relu4(float4 v) {
    v.x = fmaxf(v.x, 0.f); v.y = fmaxf(v.y, 0.f);
    v.z = fmaxf(v.z, 0.f); v.w = fmaxf(v.w, 0.f);
    return v;
}

// ---------------- f32 -> bf16 buffer convert (x -> x_bf) ----------------
__global__ void k_cvt(const float* __restrict__ in, unsigned short* __restrict__ out,
                      int n8) {
    int i = blockIdx.x * 256 + threadIdx.x;
    if (i >= n8) return;
    float4 a = reinterpret_cast<const float4*>(in)[(size_t)i * 2];
    float4 b = reinterpret_cast<const float4*>(in)[(size_t)i * 2 + 1];
    ushort4 oa, ob;
    oa.x = f2b(a.x); oa.y = f2b(a.y); oa.z = f2b(a.z); oa.w = f2b(a.w);
    ob.x = f2b(b.x); ob.y = f2b(b.y); ob.z = f2b(b.z); ob.w = f2b(b.w);
    reinterpret_cast<ushort4*>(out)[(size_t)i * 2] = oa;
    reinterpret_cast<ushort4*>(out)[(size_t)i * 2 + 1] = ob;
}

// ---------------- degree histogram ----------------
__global__ void k_hist(const int* __restrict__ dst, int* __restrict__ cnt) {
    int e = blockIdx.x * 256 + threadIdx.x;
    if (e < N_EDGES) atomicAdd(&cnt[dst[e]], 1);
}

// ---------------- exclusive scan (3 kernels) ----------------
__global__ void k_scan1(const int* __restrict__ cnt, int* __restrict__ rowptr,
                        int* __restrict__ bsums) {
    __shared__ int sd[1024];
    int tid = threadIdx.x;
    int i = blockIdx.x * 1024 + tid;
    int v = (i < N_NODES) ? cnt[i] : 0;
    sd[tid] = v;
    __syncthreads();
    for (int off = 1; off < 1024; off <<= 1) {
        int t2 = (tid >= off) ? sd[tid - off] : 0;
        __syncthreads();
        sd[tid] += t2;
        __syncthreads();
    }
    if (i < N_NODES) rowptr[i] = sd[tid] - v;
    if (tid == 1023) bsums[blockIdx.x] = sd[tid];
}

__global__ void k_scan2(int* __restrict__ bsums, int nb) {
    __shared__ int sd[128];
    int t = threadIdx.x;
    int v = (t < nb) ? bsums[t] : 0;
    sd[t] = v;
    __syncthreads();
    for (int off = 1; off < 128; off <<= 1) {
        int u = (t >= off) ? sd[t - off] : 0;
        __syncthreads();
        sd[t] += u;
        __syncthreads();
    }
    if (t < nb) bsums[t] = sd[t] - v;
}

__global__ void k_scan3(int* __restrict__ rowptr, const int* __restrict__ bsums,
                        int* __restrict__ wcur) {
    int i = blockIdx.x * 1024 + threadIdx.x;
    if (i < N_NODES) {
        int v = rowptr[i] + bsums[blockIdx.x];
        rowptr[i] = v;
        wcur[i] = v;
    }
    if (i == N_NODES - 1) rowptr[N_NODES] = N_EDGES;
}

// ---------------- bucket edges by dst (cheap, no xe access) ----------------
__global__ void k_scatter(const int* __restrict__ src, const int* __restrict__ dst,
                          int* __restrict__ wcur, int2* __restrict__ esort) {
    int e = blockIdx.x * 256 + threadIdx.x;
    if (e < N_EDGES) {
        int d = dst[e];
        int p = atomicAdd(&wcur[d], 1);
        esort[p] = make_int2(e, src[e]);
    }
}

// ---------------- gather-aggregate: one wave/node, 4 edges/half-wave --------
// MODE 0 (layer 0): read f32 xe via es.x (random), WRITE xe_s[qc] bf16 (sequential), no BN
// MODE 1 (layer 1): read xe_s[qc] bf16 (sequential), BN+relu on gathered F
// MODE 2 (layer 1 fallback): read f32 xe via es.x (random), BN+relu on gathered F
template <int MODE>
__global__ __launch_bounds__(256) void k_agg(
        const unsigned short* __restrict__ Fb, const float* __restrict__ xe,
        unsigned short* __restrict__ xe_s,
        const int* __restrict__ rowptr, const int2* __restrict__ esort,
        float* __restrict__ agg, const float* __restrict__ bnsc) {
    int wid = (blockIdx.x * 256 + threadIdx.x) >> 6;
    int lane = threadIdx.x & 63;
    if (wid >= N_NODES) return;
    int half = lane >> 5;
    int l = lane & 31;
    int p0 = rowptr[wid], p1 = rowptr[wid + 1];
    if (p0 == p1) {
        if (half == 0) {
            float4 z = make_float4(0.f, 0.f, 0.f, 0.f);
            *reinterpret_cast<float4*>(&agg[(size_t)wid * DIM + l * 4]) = z;
        }
        return;
    }
    float4 sc, sh;
    if (MODE != 0) {
        sc = *reinterpret_cast<const float4*>(&bnsc[l * 4]);
        sh = *reinterpret_cast<const float4*>(&bnsc[DIM + l * 4]);
    }
    float4 acc = make_float4(0.f, 0.f, 0.f, 0.f);
    for (int p = p0; p < p1; p += 8) {
#pragma unroll
        for (int j = 0; j < 4; ++j) {
            int q = p + j * 2 + half;
            int qc = min(q, p1 - 1);
            int2 es = esort[qc];
            float4 a = bexp4(*reinterpret_cast<const ushort4*>(
                &Fb[(size_t)es.y * DIM + l * 4]));
            float4 b;
            if (MODE == 1) {
                b = bexp4(*reinterpret_cast<const ushort4*>(
                    &xe_s[(size_t)qc * DIM + l * 4]));
            } else {
                b = *reinterpret_cast<const float4*>(
                    &xe[(size_t)es.x * DIM + l * 4]);
            }
            if (MODE != 0) {
                a.x = fmaxf(a.x * sc.x + sh.x, 0.f);
                a.y = fmaxf(a.y * sc.y + sh.y, 0.f);
                a.z = fmaxf(a.z * sc.z + sh.z, 0.f);
                a.w = fmaxf(a.w * sc.w + sh.w, 0.f);
            }
            if (q < p1) {
                if (MODE == 0) {
                    ushort4 o;
                    o.x = f2b(b.x); o.y = f2b(b.y);
                    o.z = f2b(b.z); o.w = f2b(b.w);
                    *reinterpret_cast<ushort4*>(&xe_s[(size_t)qc * DIM + l * 4]) = o;
                }
                acc.x += fmaxf(a.x + b.x, 0.f);
                acc.y += fmaxf(a.y + b.y, 0.f);
                acc.z += fmaxf(a.z + b.z, 0.f);
                acc.w += fmaxf(a.w + b.w, 0.f);
            }
        }
    }
    acc.x += __shfl_xor(acc.x, 32);
    acc.y += __shfl_xor(acc.y, 32);
    acc.z += __shfl_xor(acc.z, 32);
    acc.w += __shfl_xor(acc.w, 32);
    if (half == 0) {
        float s = 1.f / (float)(p1 - p0);
        acc.x *= s; acc.y *= s; acc.z *= s; acc.w *= s;
        *reinterpret_cast<float4*>(&agg[(size_t)wid * DIM + l * 4]) = acc;
    }
}

// ---------------- weight prep (ALL matrices in one launch) ----------------
__global__ void k_wprep_all(const float* __restrict__ Wl0, const float* __restrict__ Wr0,
                            const float* __restrict__ Wl1, const float* __restrict__ Wr1,
                            const float* __restrict__ Wp,
                            short* __restrict__ fWl0h, short* __restrict__ fWl0l,
                            short* __restrict__ fWr0h, short* __restrict__ fWr0l,
                            short* __restrict__ fWl1h, short* __restrict__ fWl1l,
                            short* __restrict__ fWr1h, short* __restrict__ fWr1l,
                            short* __restrict__ fWph, short* __restrict__ fWpl) {
    int b = blockIdx.x;          // 0..35
    const float* W; short* hi; short* lo; int ct;
    if (b < 8)       { W = Wl0; hi = fWl0h; lo = fWl0l; ct = b; }
    else if (b < 16) { W = Wr0; hi = fWr0h; lo = fWr0l; ct = b - 8; }
    else if (b < 24) { W = Wl1; hi = fWl1h; lo = fWl1l; ct = b - 16; }
    else if (b < 32) { W = Wr1; hi = fWr1h; lo = fWr1l; ct = b - 24; }
    else             { W = Wp;  hi = fWph;  lo = fWpl;  ct = b - 32; }
    int tt = threadIdx.x;
    int lane = tt & 63, ks = (tt >> 6) & 3;
    int row = ct * 16 + (lane & 15);
    int k0 = ks * 32 + ((lane >> 4) << 3);
    float4 v0 = *reinterpret_cast<const float4*>(&W[(size_t)row * DIM + k0]);
    float4 v1 = *reinterpret_cast<const float4*>(&W[(size_t)row * DIM + k0 + 4]);
    s16x8 h8, l8;
    f2hl8(v0, v1, h8, l8);
    int t = ct * 256 + ks * 64 + lane;
    *reinterpret_cast<s16x8*>(&hi[(size_t)t * 8]) = h8;
    *reinterpret_cast<s16x8*>(&lo[(size_t)t * 8]) = l8;
}

// ---------------- MFMA dual GEMM: OUT = A@W1^T + bn?(Bbf)@W2^T + bias --------
// A f32 (hi/lo split, 3 MFMA); B bf16 (2 MFMA). 2 strips/wave, 128 nodes/block.
__global__ __launch_bounds__(256) void k_gemm2(
        const float* __restrict__ A, const unsigned short* __restrict__ Bbf,
        const short* __restrict__ fW1h, const short* __restrict__ fW1l,
        const short* __restrict__ fW2h, const short* __restrict__ fW2l,
        const float* __restrict__ bias, float* __restrict__ OUTf,
        unsigned short* __restrict__ OUTb,
        float* __restrict__ bnacc, const float* __restrict__ bnsc,
        int doBN, int bnB) {
    int t = threadIdx.x, w = t >> 6, l = t & 63;
    int n0 = blockIdx.x * 128;
    int r = l & 15, kh = l >> 4;
    int row0 = n0 + w * 16 + r;
    int row1 = row0 + 64;
    int n_0 = min(row0, N_NODES - 1);
    int n_1 = min(row1, N_NODES - 1);

    f32x4 acc0[8], acc1[8];
#pragma unroll
    for (int ct = 0; ct < 8; ++ct) {
        acc0[ct] = (f32x4){0.f, 0.f, 0.f, 0.f};
        acc1[ct] = (f32x4){0.f, 0.f, 0.f, 0.f};
    }
    const s16x8* w1h = (const s16x8*)fW1h;
    const s16x8* w1l = (const s16x8*)fW1l;
    const s16x8* w2h = (const s16x8*)fW2h;
    const s16x8* w2l = (const s16x8*)fW2l;

#pragma unroll
    for (int ks = 0; ks < 4; ++ks) {
        int kb = ks * 32 + kh * 8;
        float4 va0 = *reinterpret_cast<const float4*>(&A[(size_t)n_0 * DIM + kb]);
        float4 va1 = *reinterpret_cast<const float4*>(&A[(size_t)n_0 * DIM + kb + 4]);
        float4 wa0 = *reinterpret_cast<const float4*>(&A[(size_t)n_1 * DIM + kb]);
        float4 wa1 = *reinterpret_cast<const float4*>(&A[(size_t)n_1 * DIM + kb + 4]);
        s16x8 b0 = *reinterpret_cast<const s16x8*>(&Bbf[(size_t)n_0 * DIM + kb]);
        s16x8 b1 = *reinterpret_cast<const s16x8*>(&Bbf[(size_t)n_1 * DIM + kb]);
        if (bnB) {
            float4 sc0 = *reinterpret_cast<const float4*>(&bnsc[kb]);
            float4 sh0 = *reinterpret_cast<const float4*>(&bnsc[DIM + kb]);
            float4 sc1 = *reinterpret_cast<const float4*>(&bnsc[kb + 4]);
            float4 sh1 = *reinterpret_cast<const float4*>(&bnsc[DIM + kb + 4]);
            float scv[8] = {sc0.x, sc0.y, sc0.z, sc0.w, sc1.x, sc1.y, sc1.z, sc1.w};
            float shv[8] = {sh0.x, sh0.y, sh0.z, sh0.w, sh1.x, sh1.y, sh1.z, sh1.w};
#pragma unroll
            for (int i = 0; i < 8; ++i) {
                float v = b2f((unsigned short)b0[i]);
                b0[i] = (short)f2b(fmaxf(v * scv[i] + shv[i], 0.f));
                v = b2f((unsigned short)b1[i]);
                b1[i] = (short)f2b(fmaxf(v * scv[i] + shv[i], 0.f));
            }
        }
        s16x8 a0h, a0l, a1h, a1l;
        f2hl8(va0, va1, a0h, a0l);
        f2hl8(wa0, wa1, a1h, a1l);
        int fb = ks * 64 + l;
#pragma unroll
        for (int ct = 0; ct < 8; ++ct) {
            int fi = ct * 256 + fb;
            s16x8 wh1 = w1h[fi], wl1 = w1l[fi];
            s16x8 wh2 = w2h[fi], wl2 = w2l[fi];
            acc0[ct] = MFMA_BF16(a0h, wh1, acc0[ct], 0, 0, 0);
            acc0[ct] = MFMA_BF16(a0h, wl1, acc0[ct], 0, 0, 0);
            acc0[ct] = MFMA_BF16(a0l, wh1, acc0[ct], 0, 0, 0);
            acc0[ct] = MFMA_BF16(b0, wh2, acc0[ct], 0, 0, 0);
            acc0[ct] = MFMA_BF16(b0, wl2, acc0[ct], 0, 0, 0);
            acc1[ct] = MFMA_BF16(a1h, wh1, acc1[ct], 0, 0, 0);
            acc1[ct] = MFMA_BF16(a1h, wl1, acc1[ct], 0, 0, 0);
            acc1[ct] = MFMA_BF16(a1l, wh1, acc1[ct], 0, 0, 0);
            acc1[ct] = MFMA_BF16(b1, wh2, acc1[ct], 0, 0, 0);
            acc1[ct] = MFMA_BF16(b1, wl2, acc1[ct], 0, 0, 0);
        }
    }

    // ---- epilogue: bias, store, BN partial stats ----
    float p1s[8], p2s[8];
    int col0 = l & 15;
    int nb0 = n0 + w * 16 + (kh << 2);
    int nb1 = nb0 + 64;
#pragma unroll
    for (int ct = 0; ct < 8; ++ct) {
        float bj = bias[ct * 16 + col0];
        float s1 = 0.f, s2 = 0.f;
#pragma unroll
        for (int rr = 0; rr < 4; ++rr) {
            int n = nb0 + rr;
            float h = acc0[ct][rr] + bj;
            if (n < N_NODES) {
                if (OUTb) OUTb[(size_t)n * DIM + ct * 16 + col0] = f2b(h);
                else      OUTf[(size_t)n * DIM + ct * 16 + col0] = h;
                s1 += h; s2 += h * h;
            }
            n = nb1 + rr;
            h = acc1[ct][rr] + bj;
            if (n < N_NODES) {
                if (OUTb) OUTb[(size_t)n * DIM + ct * 16 + col0] = f2b(h);
                else      OUTf[(size_t)n * DIM + ct * 16 + col0] = h;
                s1 += h; s2 += h * h;
            }
        }
        p1s[ct] = s1; p2s[ct] = s2;
    }
    if (doBN) {
        __shared__ float red1[512];
        __shared__ float red2[512];
#pragma unroll
        for (int ct = 0; ct < 8; ++ct) {
            p1s[ct] += __shfl_xor(p1s[ct], 16);
            p1s[ct] += __shfl_xor(p1s[ct], 32);
            p2s[ct] += __shfl_xor(p2s[ct], 16);
            p2s[ct] += __shfl_xor(p2s[ct], 32);
        }
        if (l < 16) {
#pragma unroll
            for (int ct = 0; ct < 8; ++ct) {
                red1[w * 128 + ct * 16 + l] = p1s[ct];
                red2[w * 128 + ct * 16 + l] = p2s[ct];
            }
        }
        __syncthreads();
        if (t < 128) {
            float s1 = red1[t] + red1[128 + t] + red1[256 + t] + red1[384 + t];
            float s2 = red2[t] + red2[128 + t] + red2[256 + t] + red2[384 + t];
            atomicAdd(&bnacc[t], s1);
            atomicAdd(&bnacc[128 + t], s2);
        }
    }
}

// ---------------- BN finalize: scale/shift vector ----------------
__global__ void k_bnfinal(const float* __restrict__ bnacc, const float* __restrict__ gamma,
                          const float* __restrict__ beta, float* __restrict__ bnsc) {
    int d = threadIdx.x;
    if (d < DIM) {
        float mu = bnacc[d] / (float)N_NODES;
        float var = bnacc[128 + d] / (float)N_NODES - mu * mu;
        float rstd = rsqrtf(var + BN_EPS);
        float sc = gamma[d] * rstd;
        bnsc[d] = sc;
        bnsc[128 + d] = beta[d] - mu * sc;
    }
}

// ---------------- graph mean pool (batch is sorted), 4 slices ----------------
__global__ void k_pool(const float* __restrict__ H1, const int* __restrict__ batch,
                       float* __restrict__ gout) {
    __shared__ float red[4][128];
    int g = blockIdx.x;
    int t = threadIdx.x;
    int d = t & 127;
    int sl = t >> 7;
    int lo = 0, hi = N_NODES;
    while (lo < hi) { int m = (lo + hi) >> 1; if (batch[m] < g) lo = m + 1; else hi = m; }
    int s = lo;
    lo = 0; hi = N_NODES;
    while (lo < hi) { int m = (lo + hi) >> 1; if (batch[m] < g + 1) lo = m + 1; else hi = m; }
    int e = lo;
    float sum = 0.f;
    for (int n = s + sl; n < e; n += 4) sum += H1[(size_t)n * DIM + d];
    red[sl][d] = sum;
    __syncthreads();
    if (t < 128) {
        float tot = red[0][d] + red[1][d] + red[2][d] + red[3][d];
        gout[g * DIM + d] = tot / (float)max(e - s, 1);
    }
}

// ---------------- MFMA projection (no LDS, 2 strips/wave) --------------------
__global__ __launch_bounds__(256) void k_proj(
        const float* __restrict__ H1, const short* __restrict__ fWph,
        const short* __restrict__ fWpl, const float* __restrict__ bp,
        float* __restrict__ OUT) {
    int t = threadIdx.x, w = t >> 6, l = t & 63;
    int n0 = blockIdx.x * 128;
    int r = l & 15, kh = l >> 4;
    int row0 = n0 + w * 16 + r;
    int row1 = row0 + 64;
    int n_0 = min(row0, N_NODES - 1);
    int n_1 = min(row1, N_NODES - 1);
    f32x4 acc0[4], acc1[4];
#pragma unroll
    for (int ct = 0; ct < 4; ++ct) {
        acc0[ct] = (f32x4){0.f, 0.f, 0.f, 0.f};
        acc1[ct] = (f32x4){0.f, 0.f, 0.f, 0.f};
    }
    const s16x8* wph = (const s16x8*)fWph;
    const s16x8* wpl = (const s16x8*)fWpl;
#pragma unroll
    for (int ks = 0; ks < 4; ++ks) {
        int kb = ks * 32 + kh * 8;
        float4 va0 = relu4(*reinterpret_cast<const float4*>(&H1[(size_t)n_0 * DIM + kb]));
        float4 va1 = relu4(*reinterpret_cast<const float4*>(&H1[(size_t)n_0 * DIM + kb + 4]));
        float4 wa0 = relu4(*reinterpret_cast<const float4*>(&H1[(size_t)n_1 * DIM + kb]));
        float4 wa1 = relu4(*reinterpret_cast<const float4*>(&H1[(size_t)n_1 * DIM + kb + 4]));
        s16x8 a0h, a0l, a1h, a1l;
        f2hl8(va0, va1, a0h, a0l);
        f2hl8(wa0, wa1, a1h, a1l);
        int fb = ks * 64 + l;
#pragma unroll
        for (int ct = 0; ct < 4; ++ct) {
            int fi = ct * 256 + fb;
            s16x8 wh = wph[fi], wl = wpl[fi];
            acc0[ct] = MFMA_BF16(a0h, wh, acc0[ct], 0, 0, 0);
            acc0[ct] = MFMA_BF16(a0h, wl, acc0[ct], 0, 0, 0);
            acc0[ct] = MFMA_BF16(a0l, wh, acc0[ct], 0, 0, 0);
            acc1[ct] = MFMA_BF16(a1h, wh, acc1[ct], 0, 0, 0);
            acc1[ct] = MFMA_BF16(a1h, wl, acc1[ct], 0, 0, 0);
            acc1[ct] = MFMA_BF16(a1l, wh, acc1[ct], 0, 0, 0);
        }
    }
    int col0 = l & 15;
    int nb0 = n0 + w * 16 + (kh << 2);
    int nb1 = nb0 + 64;
#pragma unroll
    for (int ct = 0; ct < 4; ++ct) {
        float bj = bp[ct * 16 + col0];
#pragma unroll
        for (int rr = 0; rr < 4; ++rr) {
            int n = nb0 + rr;
            if (n < N_NODES)
                OUT[(size_t)n * NCLS + ct * 16 + col0] = acc0[ct][rr] + bj;
            n = nb1 + rr;
            if (n < N_NODES)
                OUT[(size_t)n * NCLS + ct * 16 + col0] = acc1[ct][rr] + bj;
        }
    }
}

extern "C" void kernel_launch(void* const* d_in, const int* in_sizes, int n_in,
                              void* d_out, int out_size, void* d_ws, size_t ws_size,
                              hipStream_t stream) {
    (void)in_sizes; (void)n_in; (void)out_size;
    const float* x     = (const float*)d_in[0];
    const float* xe    = (const float*)d_in[1];
    const int*   eidx  = (const int*)d_in[2];
    const int*   batch = (const int*)d_in[3];
    const float* Wl0   = (const float*)d_in[4];
    const float* bl0   = (const float*)d_in[5];
    const float* Wr0   = (const float*)d_in[6];
    const float* Wl1   = (const float*)d_in[7];
    const float* bl1   = (const float*)d_in[8];
    const float* Wr1   = (const float*)d_in[9];
    const float* gamma0 = (const float*)d_in[10];
    const float* beta0  = (const float*)d_in[11];
    const float* Wp    = (const float*)d_in[12];
    const float* bp    = (const float*)d_in[13];
    const int* srcp = eidx;
    const int* dstp = eidx + N_EDGES;

    char* ws = (char*)d_ws;
    size_t off = 0;
    auto carve = [&](size_t bytes) {
        void* p = ws + off;
        off = (off + bytes + 255) & ~(size_t)255;
        return p;
    };
    int*   cnt    = (int*)carve((size_t)N_NODES * 4);
    int*   rowptr = (int*)carve((size_t)(N_NODES + 1) * 4);
    int*   wcur   = (int*)carve((size_t)N_NODES * 4);
    int*   bsums  = (int*)carve(128 * 4);
    float* bnacc  = (float*)carve(256 * 4);
    float* bnsc   = (float*)carve(256 * 4);
    int2*  esort  = (int2*)carve((size_t)N_EDGES * 8);
    float* AGG    = (float*)carve((size_t)N_NODES * DIM * 4);
    float* H1     = (float*)carve((size_t)N_NODES * DIM * 4);
    unsigned short* x_bf = (unsigned short*)carve((size_t)N_NODES * DIM * 2);
    unsigned short* H_bf = (unsigned short*)carve((size_t)N_NODES * DIM * 2);
    short* fWl0h = (short*)carve(16384 * 2);
    short* fWl0l = (short*)carve(16384 * 2);
    short* fWr0h = (short*)carve(16384 * 2);
    short* fWr0l = (short*)carve(16384 * 2);
    short* fWl1h = (short*)carve(16384 * 2);
    short* fWl1l = (short*)carve(16384 * 2);
    short* fWr1h = (short*)carve(16384 * 2);
    short* fWr1l = (short*)carve(16384 * 2);
    short* fWph  = (short*)carve(8192 * 2);
    short* fWpl  = (short*)carve(8192 * 2);

    // xe_s: bf16 edge features permuted to CSR order (written by layer-0 agg)
    size_t xes_bytes = (size_t)N_EDGES * DIM * 2;   // 409.6 MB
    int seq = (off + xes_bytes + 256 <= ws_size) ? 1 : 0;
    unsigned short* xe_s = seq ? (unsigned short*)carve(xes_bytes) : nullptr;

    float* out_h = (float*)d_out;
    float* out_g = out_h + (size_t)N_NODES * NCLS;

    hipMemsetAsync(cnt, 0, (size_t)N_NODES * 4, stream);
    hipMemsetAsync(bnacc, 0, 256 * 4, stream);

    k_wprep_all<<<36, 256, 0, stream>>>(Wl0, Wr0, Wl1, Wr1, Wp,
                                        fWl0h, fWl0l, fWr0h, fWr0l,
                                        fWl1h, fWl1l, fWr1h, fWr1l,
                                        fWph, fWpl);
    k_cvt<<<(N_NODES * DIM / 8 + 255) / 256, 256, 0, stream>>>(x, x_bf,
                                                               N_NODES * DIM / 8);

    int nb = (N_NODES + 1023) / 1024;  // 98
    k_hist<<<(N_EDGES + 255) / 256, 256, 0, stream>>>(dstp, cnt);
    k_scan1<<<nb, 1024, 0, stream>>>(cnt, rowptr, bsums);
    k_scan2<<<1, 128, 0, stream>>>(bsums, nb);
    k_scan3<<<nb, 1024, 0, stream>>>(rowptr, bsums, wcur);
    k_scatter<<<(N_EDGES + 255) / 256, 256, 0, stream>>>(srcp, dstp, wcur, esort);

    int ablocks = (N_NODES * 64 + 255) / 256;
    int gblocks = (N_NODES + 127) / 128;  // 782

    // layer 0: agg reads f32 xe (random), writes xe_s (sequential, bf16)
    if (seq)
        k_agg<0><<<ablocks, 256, 0, stream>>>(x_bf, xe, xe_s, rowptr, esort, AGG, bnsc);
    else
        k_agg<2><<<ablocks, 256, 0, stream>>>(x_bf, xe, nullptr, rowptr, esort, AGG, bnsc);
    k_gemm2<<<gblocks, 256, 0, stream>>>(AGG, x_bf, fWl0h, fWl0l, fWr0h, fWr0l,
                                         bl0, nullptr, H_bf, bnacc, bnsc, 1, 0);
    k_bnfinal<<<1, 128, 0, stream>>>(bnacc, gamma0, beta0, bnsc);

    // layer 1: agg reads xe_s sequentially (bf16), BN+relu fused on gathered H
    if (seq)
        k_agg<1><<<ablocks, 256, 0, stream>>>(H_bf, xe, xe_s, rowptr, esort, AGG, bnsc);
    else
        k_agg<2><<<ablocks, 256, 0, stream>>>(H_bf, xe, nullptr, rowptr, esort, AGG, bnsc);
    k_gemm2<<<gblocks, 256, 0, stream>>>(AGG, H_bf, fWl1h, fWl1l, fWr1h, fWr1l,
                                         bl1, H1, nullptr, bnacc, bnsc, 0, 1);

    // readout
    k_pool<<<NG, 512, 0, stream>>>(H1, batch, out_g);
    k_proj<<<gblocks, 256, 0, stream>>>(H1, fWph, fWpl, bp, out_h);
}

// Round 9
// 862.504 us; speedup vs baseline: 6.6409x; 1.0042x over previous
//
#include <hip/hip_runtime.h>

#define N_NODES 100000
#define N_EDGES 1600000
#define DIM 128
#define NCLS 64
#define NG 128
#define BN_EPS 1e-5f

typedef __attribute__((ext_vector_type(8))) short s16x8;
typedef __attribute__((ext_vector_type(4))) float f32x4;
#define MFMA_BF16 __builtin_amdgcn_mfma_f32_16x16x32_bf16

// f32 -> bf16 RNE
__device__ __forceinline__ unsigned short f2b(float x) {
    unsigned u = __float_as_uint(x);
    return (unsigned short)((u + 0x7FFFu + ((u >> 16) & 1u)) >> 16);
}
__device__ __forceinline__ float b2f(unsigned short s) {
    return __uint_as_float(((unsigned)s) << 16);
}
__device__ __forceinline__ float4 bexp4(ushort4 u) {
    float4 f;
    f.x = b2f(u.x); f.y = b2f(u.y); f.z = b2f(u.z); f.w = b2f(u.w);
    return f;
}

// split 8 f32 into bf16 hi + bf16 lo (truncation; hi+lo ~exact to 2^-16 rel)
__device__ __forceinline__ void f2hl8(float4 v0, float4 v1, s16x8& h8, s16x8& l8) {
    float vv[8] = {v0.x, v0.y, v0.z, v0.w, v1.x, v1.y, v1.z, v1.w};
#pragma unroll
    for (int i = 0; i < 8; ++i) {
        unsigned u = __float_as_uint(vv[i]);
        short h = (short)(u >> 16);
        float r = vv[i] - __uint_as_float(u & 0xFFFF0000u);
        short l = (short)(__float_as_uint(r) >> 16);
        h8[i] = h;
        l8[i] = l;
    }
}

// ---------------- mega kernel 0: wprep(36) | cvt x->x_bf(6250) | hist(6250) ----
__global__ __launch_bounds__(256) void k_mega0(
        const float* __restrict__ Wl0, const float* __restrict__ Wr0,
        const float* __restrict__ Wl1, const float* __restrict__ Wr1,
        const float* __restrict__ Wp,
        short* __restrict__ fWl0h, short* __restrict__ fWl0l,
        short* __restrict__ fWr0h, short* __restrict__ fWr0l,
        short* __restrict__ fWl1h, short* __restrict__ fWl1l,
        short* __restrict__ fWr1h, short* __restrict__ fWr1l,
        short* __restrict__ fWph, short* __restrict__ fWpl,
        const float* __restrict__ x, unsigned short* __restrict__ x_bf,
        const int* __restrict__ dst, int* __restrict__ cnt) {
    int b = blockIdx.x;
    if (b < 36) {
        // weight prep: frag t = ct*256+ks*64+lane holds W[col][k]
        const float* W; short* hi; short* lo; int ct;
        if (b < 8)       { W = Wl0; hi = fWl0h; lo = fWl0l; ct = b; }
        else if (b < 16) { W = Wr0; hi = fWr0h; lo = fWr0l; ct = b - 8; }
        else if (b < 24) { W = Wl1; hi = fWl1h; lo = fWl1l; ct = b - 16; }
        else if (b < 32) { W = Wr1; hi = fWr1h; lo = fWr1l; ct = b - 24; }
        else             { W = Wp;  hi = fWph;  lo = fWpl;  ct = b - 32; }
        if (b >= 32 && ct >= 4) return;
        int tt = threadIdx.x;
        int lane = tt & 63, ks = (tt >> 6) & 3;
        int row = ct * 16 + (lane & 15);
        int k0 = ks * 32 + ((lane >> 4) << 3);
        float4 v0 = *reinterpret_cast<const float4*>(&W[(size_t)row * DIM + k0]);
        float4 v1 = *reinterpret_cast<const float4*>(&W[(size_t)row * DIM + k0 + 4]);
        s16x8 h8, l8;
        f2hl8(v0, v1, h8, l8);
        int t = ct * 256 + ks * 64 + lane;
        *reinterpret_cast<s16x8*>(&hi[(size_t)t * 8]) = h8;
        *reinterpret_cast<s16x8*>(&lo[(size_t)t * 8]) = l8;
    } else if (b < 36 + 6250) {
        int i = (b - 36) * 256 + threadIdx.x;   // float8 index, exactly 1.6M
        float4 a = reinterpret_cast<const float4*>(x)[(size_t)i * 2];
        float4 c = reinterpret_cast<const float4*>(x)[(size_t)i * 2 + 1];
        ushort4 oa, ob;
        oa.x = f2b(a.x); oa.y = f2b(a.y); oa.z = f2b(a.z); oa.w = f2b(a.w);
        ob.x = f2b(c.x); ob.y = f2b(c.y); ob.z = f2b(c.z); ob.w = f2b(c.w);
        reinterpret_cast<ushort4*>(x_bf)[(size_t)i * 2] = oa;
        reinterpret_cast<ushort4*>(x_bf)[(size_t)i * 2 + 1] = ob;
    } else {
        int e = (b - 36 - 6250) * 256 + threadIdx.x;  // exactly 1.6M
        atomicAdd(&cnt[dst[e]], 1);
    }
}

// ---------------- exclusive scan (3 kernels) ----------------
__global__ void k_scan1(const int* __restrict__ cnt, int* __restrict__ rowptr,
                        int* __restrict__ bsums) {
    __shared__ int sd[1024];
    int tid = threadIdx.x;
    int i = blockIdx.x * 1024 + tid;
    int v = (i < N_NODES) ? cnt[i] : 0;
    sd[tid] = v;
    __syncthreads();
    for (int off = 1; off < 1024; off <<= 1) {
        int t2 = (tid >= off) ? sd[tid - off] : 0;
        __syncthreads();
        sd[tid] += t2;
        __syncthreads();
    }
    if (i < N_NODES) rowptr[i] = sd[tid] - v;
    if (tid == 1023) bsums[blockIdx.x] = sd[tid];
}

__global__ void k_scan2(int* __restrict__ bsums, int nb) {
    __shared__ int sd[128];
    int t = threadIdx.x;
    int v = (t < nb) ? bsums[t] : 0;
    sd[t] = v;
    __syncthreads();
    for (int off = 1; off < 128; off <<= 1) {
        int u = (t >= off) ? sd[t - off] : 0;
        __syncthreads();
        sd[t] += u;
        __syncthreads();
    }
    if (t < nb) bsums[t] = sd[t] - v;
}

__global__ void k_scan3(int* __restrict__ rowptr, const int* __restrict__ bsums,
                        int* __restrict__ wcur) {
    int i = blockIdx.x * 1024 + threadIdx.x;
    if (i < N_NODES) {
        int v = rowptr[i] + bsums[blockIdx.x];
        rowptr[i] = v;
        wcur[i] = v;
    }
    if (i == N_NODES - 1) rowptr[N_NODES] = N_EDGES;
}

// ---------------- bucket edges by dst ----------------
__global__ void k_scatter(const int* __restrict__ src, const int* __restrict__ dst,
                          int* __restrict__ wcur, int2* __restrict__ esort) {
    int e = blockIdx.x * 256 + threadIdx.x;
    if (e < N_EDGES) {
        int d = dst[e];
        int p = atomicAdd(&wcur[d], 1);
        esort[p] = make_int2(e, src[e]);
    }
}

// ---------------- gather-aggregate: one wave/node, 4 edges/half-wave --------
// MODE 0: read f32 xe random, WRITE xe_s bf16 sequential, no BN.  AGG out bf16.
// MODE 1: read xe_s bf16 sequential, BN+relu on gathered F.
// MODE 2: fallback, read f32 xe random, BN+relu on gathered F.
template <int MODE>
__global__ __launch_bounds__(256) void k_agg(
        const unsigned short* __restrict__ Fb, const float* __restrict__ xe,
        unsigned short* __restrict__ xe_s,
        const int* __restrict__ rowptr, const int2* __restrict__ esort,
        unsigned short* __restrict__ agg, const float* __restrict__ bnsc) {
    int wid = (blockIdx.x * 256 + threadIdx.x) >> 6;
    int lane = threadIdx.x & 63;
    if (wid >= N_NODES) return;
    int half = lane >> 5;
    int l = lane & 31;
    int p0 = rowptr[wid], p1 = rowptr[wid + 1];
    if (p0 == p1) {
        if (half == 0) {
            ushort4 z = make_ushort4(0, 0, 0, 0);
            *reinterpret_cast<ushort4*>(&agg[(size_t)wid * DIM + l * 4]) = z;
        }
        return;
    }
    float4 sc, sh;
    if (MODE != 0) {
        sc = *reinterpret_cast<const float4*>(&bnsc[l * 4]);
        sh = *reinterpret_cast<const float4*>(&bnsc[DIM + l * 4]);
    }
    float4 acc = make_float4(0.f, 0.f, 0.f, 0.f);
    for (int p = p0; p < p1; p += 8) {
#pragma unroll
        for (int j = 0; j < 4; ++j) {
            int q = p + j * 2 + half;
            int qc = min(q, p1 - 1);
            int2 es = esort[qc];
            float4 a = bexp4(*reinterpret_cast<const ushort4*>(
                &Fb[(size_t)es.y * DIM + l * 4]));
            float4 b;
            if (MODE == 1) {
                b = bexp4(*reinterpret_cast<const ushort4*>(
                    &xe_s[(size_t)qc * DIM + l * 4]));
            } else {
                b = *reinterpret_cast<const float4*>(
                    &xe[(size_t)es.x * DIM + l * 4]);
            }
            if (MODE != 0) {
                a.x = fmaxf(a.x * sc.x + sh.x, 0.f);
                a.y = fmaxf(a.y * sc.y + sh.y, 0.f);
                a.z = fmaxf(a.z * sc.z + sh.z, 0.f);
                a.w = fmaxf(a.w * sc.w + sh.w, 0.f);
            }
            if (q < p1) {
                if (MODE == 0) {
                    ushort4 o;
                    o.x = f2b(b.x); o.y = f2b(b.y);
                    o.z = f2b(b.z); o.w = f2b(b.w);
                    *reinterpret_cast<ushort4*>(&xe_s[(size_t)qc * DIM + l * 4]) = o;
                }
                acc.x += fmaxf(a.x + b.x, 0.f);
                acc.y += fmaxf(a.y + b.y, 0.f);
                acc.z += fmaxf(a.z + b.z, 0.f);
                acc.w += fmaxf(a.w + b.w, 0.f);
            }
        }
    }
    acc.x += __shfl_xor(acc.x, 32);
    acc.y += __shfl_xor(acc.y, 32);
    acc.z += __shfl_xor(acc.z, 32);
    acc.w += __shfl_xor(acc.w, 32);
    if (half == 0) {
        float s = 1.f / (float)(p1 - p0);
        ushort4 o;
        o.x = f2b(acc.x * s); o.y = f2b(acc.y * s);
        o.z = f2b(acc.z * s); o.w = f2b(acc.w * s);
        *reinterpret_cast<ushort4*>(&agg[(size_t)wid * DIM + l * 4]) = o;
    }
}

// ---------------- MFMA dual GEMM: OUT = Abf@W1^T + bn?(Bbf)@W2^T + bias ------
// A,B bf16 (2 MFMA each side). 2 strips/wave, 128 nodes/block. Output bf16.
__global__ __launch_bounds__(256) void k_gemm2(
        const unsigned short* __restrict__ Abf, const unsigned short* __restrict__ Bbf,
        const short* __restrict__ fW1h, const short* __restrict__ fW1l,
        const short* __restrict__ fW2h, const short* __restrict__ fW2l,
        const float* __restrict__ bias, unsigned short* __restrict__ OUTb,
        float* __restrict__ bnacc, const float* __restrict__ bnsc,
        int doBN, int bnB) {
    int t = threadIdx.x, w = t >> 6, l = t & 63;
    int n0 = blockIdx.x * 128;
    int r = l & 15, kh = l >> 4;
    int row0 = n0 + w * 16 + r;
    int row1 = row0 + 64;
    int n_0 = min(row0, N_NODES - 1);
    int n_1 = min(row1, N_NODES - 1);

    f32x4 acc0[8], acc1[8];
#pragma unroll
    for (int ct = 0; ct < 8; ++ct) {
        acc0[ct] = (f32x4){0.f, 0.f, 0.f, 0.f};
        acc1[ct] = (f32x4){0.f, 0.f, 0.f, 0.f};
    }
    const s16x8* w1h = (const s16x8*)fW1h;
    const s16x8* w1l = (const s16x8*)fW1l;
    const s16x8* w2h = (const s16x8*)fW2h;
    const s16x8* w2l = (const s16x8*)fW2l;

#pragma unroll
    for (int ks = 0; ks < 4; ++ks) {
        int kb = ks * 32 + kh * 8;
        s16x8 a0 = *reinterpret_cast<const s16x8*>(&Abf[(size_t)n_0 * DIM + kb]);
        s16x8 a1 = *reinterpret_cast<const s16x8*>(&Abf[(size_t)n_1 * DIM + kb]);
        s16x8 b0 = *reinterpret_cast<const s16x8*>(&Bbf[(size_t)n_0 * DIM + kb]);
        s16x8 b1 = *reinterpret_cast<const s16x8*>(&Bbf[(size_t)n_1 * DIM + kb]);
        if (bnB) {
            float4 sc0 = *reinterpret_cast<const float4*>(&bnsc[kb]);
            float4 sh0 = *reinterpret_cast<const float4*>(&bnsc[DIM + kb]);
            float4 sc1 = *reinterpret_cast<const float4*>(&bnsc[kb + 4]);
            float4 sh1 = *reinterpret_cast<const float4*>(&bnsc[DIM + kb + 4]);
            float scv[8] = {sc0.x, sc0.y, sc0.z, sc0.w, sc1.x, sc1.y, sc1.z, sc1.w};
            float shv[8] = {sh0.x, sh0.y, sh0.z, sh0.w, sh1.x, sh1.y, sh1.z, sh1.w};
#pragma unroll
            for (int i = 0; i < 8; ++i) {
                float v = b2f((unsigned short)b0[i]);
                b0[i] = (short)f2b(fmaxf(v * scv[i] + shv[i], 0.f));
                v = b2f((unsigned short)b1[i]);
                b1[i] = (short)f2b(fmaxf(v * scv[i] + shv[i], 0.f));
            }
        }
        int fb = ks * 64 + l;
#pragma unroll
        for (int ct = 0; ct < 8; ++ct) {
            int fi = ct * 256 + fb;
            s16x8 wh1 = w1h[fi], wl1 = w1l[fi];
            s16x8 wh2 = w2h[fi], wl2 = w2l[fi];
            acc0[ct] = MFMA_BF16(a0, wh1, acc0[ct], 0, 0, 0);
            acc0[ct] = MFMA_BF16(a0, wl1, acc0[ct], 0, 0, 0);
            acc0[ct] = MFMA_BF16(b0, wh2, acc0[ct], 0, 0, 0);
            acc0[ct] = MFMA_BF16(b0, wl2, acc0[ct], 0, 0, 0);
            acc1[ct] = MFMA_BF16(a1, wh1, acc1[ct], 0, 0, 0);
            acc1[ct] = MFMA_BF16(a1, wl1, acc1[ct], 0, 0, 0);
            acc1[ct] = MFMA_BF16(b1, wh2, acc1[ct], 0, 0, 0);
            acc1[ct] = MFMA_BF16(b1, wl2, acc1[ct], 0, 0, 0);
        }
    }

    // ---- epilogue: bias, bf16 store, BN partial stats ----
    float p1s[8], p2s[8];
    int col0 = l & 15;
    int nb0 = n0 + w * 16 + (kh << 2);
    int nb1 = nb0 + 64;
#pragma unroll
    for (int ct = 0; ct < 8; ++ct) {
        float bj = bias[ct * 16 + col0];
        float s1 = 0.f, s2 = 0.f;
#pragma unroll
        for (int rr = 0; rr < 4; ++rr) {
            int n = nb0 + rr;
            float h = acc0[ct][rr] + bj;
            if (n < N_NODES) {
                OUTb[(size_t)n * DIM + ct * 16 + col0] = f2b(h);
                s1 += h; s2 += h * h;
            }
            n = nb1 + rr;
            h = acc1[ct][rr] + bj;
            if (n < N_NODES) {
                OUTb[(size_t)n * DIM + ct * 16 + col0] = f2b(h);
                s1 += h; s2 += h * h;
            }
        }
        p1s[ct] = s1; p2s[ct] = s2;
    }
    if (doBN) {
        __shared__ float red1[512];
        __shared__ float red2[512];
#pragma unroll
        for (int ct = 0; ct < 8; ++ct) {
            p1s[ct] += __shfl_xor(p1s[ct], 16);
            p1s[ct] += __shfl_xor(p1s[ct], 32);
            p2s[ct] += __shfl_xor(p2s[ct], 16);
            p2s[ct] += __shfl_xor(p2s[ct], 32);
        }
        if (l < 16) {
#pragma unroll
            for (int ct = 0; ct < 8; ++ct) {
                red1[w * 128 + ct * 16 + l] = p1s[ct];
                red2[w * 128 + ct * 16 + l] = p2s[ct];
            }
        }
        __syncthreads();
        if (t < 128) {
            float s1 = red1[t] + red1[128 + t] + red1[256 + t] + red1[384 + t];
            float s2 = red2[t] + red2[128 + t] + red2[256 + t] + red2[384 + t];
            atomicAdd(&bnacc[t], s1);
            atomicAdd(&bnacc[128 + t], s2);
        }
    }
}

// ---------------- BN finalize: scale/shift vector ----------------
__global__ void k_bnfinal(const float* __restrict__ bnacc, const float* __restrict__ gamma,
                          const float* __restrict__ beta, float* __restrict__ bnsc) {
    int d = threadIdx.x;
    if (d < DIM) {
        float mu = bnacc[d] / (float)N_NODES;
        float var = bnacc[128 + d] / (float)N_NODES - mu * mu;
        float rstd = rsqrtf(var + BN_EPS);
        float sc = gamma[d] * rstd;
        bnsc[d] = sc;
        bnsc[128 + d] = beta[d] - mu * sc;
    }
}

// ---------------- graph mean pool (batch sorted), bf16 input ----------------
__global__ void k_pool(const unsigned short* __restrict__ H1b,
                       const int* __restrict__ batch, float* __restrict__ gout) {
    __shared__ float red[4][128];
    int g = blockIdx.x;
    int t = threadIdx.x;
    int d = t & 127;
    int sl = t >> 7;
    int lo = 0, hi = N_NODES;
    while (lo < hi) { int m = (lo + hi) >> 1; if (batch[m] < g) lo = m + 1; else hi = m; }
    int s = lo;
    lo = 0; hi = N_NODES;
    while (lo < hi) { int m = (lo + hi) >> 1; if (batch[m] < g + 1) lo = m + 1; else hi = m; }
    int e = lo;
    float sum = 0.f;
    for (int n = s + sl; n < e; n += 4) sum += b2f(H1b[(size_t)n * DIM + d]);
    red[sl][d] = sum;
    __syncthreads();
    if (t < 128) {
        float tot = red[0][d] + red[1][d] + red[2][d] + red[3][d];
        gout[g * DIM + d] = tot / (float)max(e - s, 1);
    }
}

// ---------------- MFMA projection from bf16 H1b (relu exact in bf16) --------
__global__ __launch_bounds__(256) void k_proj(
        const unsigned short* __restrict__ H1b, const short* __restrict__ fWph,
        const short* __restrict__ fWpl, const float* __restrict__ bp,
        float* __restrict__ OUT) {
    int t = threadIdx.x, w = t >> 6, l = t & 63;
    int n0 = blockIdx.x * 128;
    int r = l & 15, kh = l >> 4;
    int row0 = n0 + w * 16 + r;
    int row1 = row0 + 64;
    int n_0 = min(row0, N_NODES - 1);
    int n_1 = min(row1, N_NODES - 1);
    f32x4 acc0[4], acc1[4];
#pragma unroll
    for (int ct = 0; ct < 4; ++ct) {
        acc0[ct] = (f32x4){0.f, 0.f, 0.f, 0.f};
        acc1[ct] = (f32x4){0.f, 0.f, 0.f, 0.f};
    }
    const s16x8* wph = (const s16x8*)fWph;
    const s16x8* wpl = (const s16x8*)fWpl;
#pragma unroll
    for (int ks = 0; ks < 4; ++ks) {
        int kb = ks * 32 + kh * 8;
        s16x8 r0 = *reinterpret_cast<const s16x8*>(&H1b[(size_t)n_0 * DIM + kb]);
        s16x8 r1 = *reinterpret_cast<const s16x8*>(&H1b[(size_t)n_1 * DIM + kb]);
        s16x8 a0, a1;
#pragma unroll
        for (int i = 0; i < 8; ++i) {
            a0[i] = r0[i] < 0 ? (short)0 : r0[i];   // relu on bf16 = sign test
            a1[i] = r1[i] < 0 ? (short)0 : r1[i];
        }
        int fb = ks * 64 + l;
#pragma unroll
        for (int ct = 0; ct < 4; ++ct) {
            int fi = ct * 256 + fb;
            s16x8 wh = wph[fi], wl = wpl[fi];
            acc0[ct] = MFMA_BF16(a0, wh, acc0[ct], 0, 0, 0);
            acc0[ct] = MFMA_BF16(a0, wl, acc0[ct], 0, 0, 0);
            acc1[ct] = MFMA_BF16(a1, wh, acc1[ct], 0, 0, 0);
            acc1[ct] = MFMA_BF16(a1, wl, acc1[ct], 0, 0, 0);
        }
    }
    int col0 = l & 15;
    int nb0 = n0 + w * 16 + (kh << 2);
    int nb1 = nb0 + 64;
#pragma unroll
    for (int ct = 0; ct < 4; ++ct) {
        float bj = bp[ct * 16 + col0];
#pragma unroll
        for (int rr = 0; rr < 4; ++rr) {
            int n = nb0 + rr;
            if (n < N_NODES)
                OUT[(size_t)n * NCLS + ct * 16 + col0] = acc0[ct][rr] + bj;
            n = nb1 + rr;
            if (n < N_NODES)
                OUT[(size_t)n * NCLS + ct * 16 + col0] = acc1[ct][rr] + bj;
        }
    }
}

extern "C" void kernel_launch(void* const* d_in, const int* in_sizes, int n_in,
                              void* d_out, int out_size, void* d_ws, size_t ws_size,
                              hipStream_t stream) {
    (void)in_sizes; (void)n_in; (void)out_size;
    const float* x     = (const float*)d_in[0];
    const float* xe    = (const float*)d_in[1];
    const int*   eidx  = (const int*)d_in[2];
    const int*   batch = (const int*)d_in[3];
    const float* Wl0   = (const float*)d_in[4];
    const float* bl0   = (const float*)d_in[5];
    const float* Wr0   = (const float*)d_in[6];
    const float* Wl1   = (const float*)d_in[7];
    const float* bl1   = (const float*)d_in[8];
    const float* Wr1   = (const float*)d_in[9];
    const float* gamma0 = (const float*)d_in[10];
    const float* beta0  = (const float*)d_in[11];
    const float* Wp    = (const float*)d_in[12];
    const float* bp    = (const float*)d_in[13];
    const int* srcp = eidx;
    const int* dstp = eidx + N_EDGES;

    char* ws = (char*)d_ws;
    size_t off = 0;
    auto carve = [&](size_t bytes) {
        void* p = ws + off;
        off = (off + bytes + 255) & ~(size_t)255;
        return p;
    };
    int*   cnt    = (int*)carve((size_t)N_NODES * 4);
    int*   rowptr = (int*)carve((size_t)(N_NODES + 1) * 4);
    int*   wcur   = (int*)carve((size_t)N_NODES * 4);
    int*   bsums  = (int*)carve(128 * 4);
    float* bnacc  = (float*)carve(256 * 4);
    float* bnsc   = (float*)carve(256 * 4);
    int2*  esort  = (int2*)carve((size_t)N_EDGES * 8);
    unsigned short* AGGb = (unsigned short*)carve((size_t)N_NODES * DIM * 2);
    unsigned short* x_bf = (unsigned short*)carve((size_t)N_NODES * DIM * 2);
    unsigned short* H_bf = (unsigned short*)carve((size_t)N_NODES * DIM * 2);
    unsigned short* H1b  = (unsigned short*)carve((size_t)N_NODES * DIM * 2);
    short* fWl0h = (short*)carve(16384 * 2);
    short* fWl0l = (short*)carve(16384 * 2);
    short* fWr0h = (short*)carve(16384 * 2);
    short* fWr0l = (short*)carve(16384 * 2);
    short* fWl1h = (short*)carve(16384 * 2);
    short* fWl1l = (short*)carve(16384 * 2);
    short* fWr1h = (short*)carve(16384 * 2);
    short* fWr1l = (short*)carve(16384 * 2);
    short* fWph  = (short*)carve(8192 * 2);
    short* fWpl  = (short*)carve(8192 * 2);

    size_t xes_bytes = (size_t)N_EDGES * DIM * 2;   // 409.6 MB
    int seq = (off + xes_bytes + 256 <= ws_size) ? 1 : 0;
    unsigned short* xe_s = seq ? (unsigned short*)carve(xes_bytes) : nullptr;

    float* out_h = (float*)d_out;
    float* out_g = out_h + (size_t)N_NODES * NCLS;

    hipMemsetAsync(cnt, 0, (size_t)N_NODES * 4, stream);
    hipMemsetAsync(bnacc, 0, 256 * 4, stream);

    // fused: weight prep | x->bf16 | degree histogram
    k_mega0<<<36 + 6250 + 6250, 256, 0, stream>>>(
        Wl0, Wr0, Wl1, Wr1, Wp,
        fWl0h, fWl0l, fWr0h, fWr0l, fWl1h, fWl1l, fWr1h, fWr1l, fWph, fWpl,
        x, x_bf, dstp, cnt);

    int nb = (N_NODES + 1023) / 1024;  // 98
    k_scan1<<<nb, 1024, 0, stream>>>(cnt, rowptr, bsums);
    k_scan2<<<1, 128, 0, stream>>>(bsums, nb);
    k_scan3<<<nb, 1024, 0, stream>>>(rowptr, bsums, wcur);
    k_scatter<<<(N_EDGES + 255) / 256, 256, 0, stream>>>(srcp, dstp, wcur, esort);

    int ablocks = (N_NODES * 64 + 255) / 256;   // 25000
    int gblocks = (N_NODES + 127) / 128;        // 782

    // layer 0: agg reads f32 xe (random), writes xe_s bf16 (sequential)
    if (seq)
        k_agg<0><<<ablocks, 256, 0, stream>>>(x_bf, xe, xe_s, rowptr, esort, AGGb, bnsc);
    else
        k_agg<2><<<ablocks, 256, 0, stream>>>(x_bf, xe, nullptr, rowptr, esort, AGGb, bnsc);
    k_gemm2<<<gblocks, 256, 0, stream>>>(AGGb, x_bf, fWl0h, fWl0l, fWr0h, fWr0l,
                                         bl0, H_bf, bnacc, bnsc, 1, 0);
    k_bnfinal<<<1, 128, 0, stream>>>(bnacc, gamma0, beta0, bnsc);

    // layer 1: agg reads xe_s sequentially, BN+relu fused on gathered H
    if (seq)
        k_agg<1><<<ablocks, 256, 0, stream>>>(H_bf, xe, xe_s, rowptr, esort, AGGb, bnsc);
    else
        k_agg<2><<<ablocks, 256, 0, stream>>>(H_bf, xe, nullptr, rowptr, esort, AGGb, bnsc);
    k_gemm2<<<gblocks, 256, 0, stream>>>(AGGb, H_bf, fWl1h, fWl1l, fWr1h, fWr1l,
                                         bl1, H1b, bnacc, bnsc, 0, 1);

    // readout (both from bf16 H1b; proj relu exact in bf16)
    k_pool<<<NG, 512, 0, stream>>>(H1b, batch, out_g);
    k_proj<<<gblocks, 256, 0, stream>>>(H1b, fWph, fWpl, bp, out_h);
}